// Round 5
// baseline (44909.384 us; speedup 1.0000x reference)
//
#include <hip/hip_runtime.h>
#include <math.h>

// Problem constants
#define SB   64     // batch
#define SN   128    // seq len
#define SE   1024   // feature dim
#define SD   256    // hidden D
#define SD2  512    // 2D
#define SD3  768    // 3D
#define SIN  2048   // 4D+E
#define SNC  7
#define SBN  8192   // SB*SN
#define CS   16     // chunk steps for gate precompute

__device__ __forceinline__ float wsum(float v){
#pragma unroll
  for (int o = 32; o; o >>= 1) v += __shfl_xor(v, o);
  return v;
}
__device__ __forceinline__ float sigm(float x){ return 1.f/(1.f + expf(-x)); }

// ---------------------------------------------------------------------------
// Generic fp32 GEMM: C[M,N] = A @ op(B) (+bias)(+acc)(+relu), batched via z.
// BKMAJ=false: B rows are N (NT).  BKMAJ=true: B rows are K (NN).
// BM=128, BN=64, BK=16, 256 threads, 8x4 micro-tile.
// ---------------------------------------------------------------------------
template<bool BKMAJ, bool BIAS, bool RELU, bool ACC>
__global__ __launch_bounds__(256)
void gemm_k(const float* __restrict__ A, const float* __restrict__ Bm,
            const float* __restrict__ bias, float* __restrict__ C,
            int Nn, int K, int lda, int ldb, int ldc,
            long sA, long sB, long sC)
{
  __shared__ float As[16][132];
  __shared__ float Bs[16][68];
  const int t  = threadIdx.x;
  const int tx = t & 15, ty = t >> 4;
  const float* Ab = A + (long)blockIdx.z * sA;
  const float* Bb = Bm + (long)blockIdx.z * sB;
  float* Cb = C + (long)blockIdx.z * sC;
  const int m0 = blockIdx.y * 128, n0 = blockIdx.x * 64;
  float acc[8][4];
#pragma unroll
  for (int i = 0; i < 8; ++i)
#pragma unroll
    for (int j = 0; j < 4; ++j) acc[i][j] = 0.f;

  const int am = t >> 1, ak = (t & 1) * 8;
  int bn_ = 0, bk_ = 0;
  if (BKMAJ) { bk_ = t >> 4; bn_ = (t & 15) * 4; }
  else       { bn_ = t >> 2; bk_ = (t & 3) * 4; }

  for (int k0 = 0; k0 < K; k0 += 16) {
    const float4 a0 = *(const float4*)(Ab + (long)(m0 + am) * lda + k0 + ak);
    const float4 a1 = *(const float4*)(Ab + (long)(m0 + am) * lda + k0 + ak + 4);
    float4 b0;
    if (BKMAJ) b0 = *(const float4*)(Bb + (long)(k0 + bk_) * ldb + n0 + bn_);
    else       b0 = *(const float4*)(Bb + (long)(n0 + bn_) * ldb + k0 + bk_);
    __syncthreads();
    As[ak+0][am] = a0.x; As[ak+1][am] = a0.y; As[ak+2][am] = a0.z; As[ak+3][am] = a0.w;
    As[ak+4][am] = a1.x; As[ak+5][am] = a1.y; As[ak+6][am] = a1.z; As[ak+7][am] = a1.w;
    if (BKMAJ) { *(float4*)&Bs[bk_][bn_] = b0; }
    else { Bs[bk_+0][bn_] = b0.x; Bs[bk_+1][bn_] = b0.y; Bs[bk_+2][bn_] = b0.z; Bs[bk_+3][bn_] = b0.w; }
    __syncthreads();
#pragma unroll
    for (int kk = 0; kk < 16; ++kk) {
      float av[8], bv[4];
      *(float4*)&av[0] = *(const float4*)&As[kk][ty*8];
      *(float4*)&av[4] = *(const float4*)&As[kk][ty*8+4];
      *(float4*)&bv[0] = *(const float4*)&Bs[kk][tx*4];
#pragma unroll
      for (int ii = 0; ii < 8; ++ii)
#pragma unroll
        for (int jj = 0; jj < 4; ++jj)
          acc[ii][jj] = fmaf(av[ii], bv[jj], acc[ii][jj]);
    }
  }
#pragma unroll
  for (int ii = 0; ii < 8; ++ii) {
#pragma unroll
    for (int jj = 0; jj < 4; ++jj) {
      float v = acc[ii][jj];
      if (BIAS) v += bias[n0 + tx*4 + jj];
      const long ci = (long)(m0 + ty*8 + ii) * ldc + n0 + tx*4 + jj;
      if (ACC) v += Cb[ci];
      if (RELU) v = fmaxf(v, 0.f);
      Cb[ci] = v;
    }
  }
}

// Htmp is b-major (row b*128+n). Write time-major X0f[(n*64+b)] and reversed.
__global__ void spread_k(const float* __restrict__ src, float* __restrict__ xf,
                         float* __restrict__ xr)
{
  const int r = blockIdx.x, t = threadIdx.x;   // src row = b*128+n
  const int b = r >> 7, n = r & 127;
  const float v = src[(long)r * SD + t];
  xf[((long)(n * 64 + b)) * SD + t] = v;
  xr[((long)((127 - n) * 64 + b)) * SD + t] = v;
}

// Pack per-layer GK weights: Wpk[cd] = [cwih(768x256); pwhh(768x256)],
// bpk[cd] = [cbih; pbhh]. Grid (1536, 4cd).
struct PkArgs {
  const float* wA[4]; const float* wB[4];
  const float* bA[4]; const float* bB[4];
  float* Wpk; float* bpk;
};
__global__ void pack_k(PkArgs a)
{
  const int cd = blockIdx.y, r = blockIdx.x, t = threadIdx.x;
  const float* src = (r < 768) ? (a.wA[cd] + (long)r * SD)
                               : (a.wB[cd] + (long)(r - 768) * SD);
  a.Wpk[((long)cd * 1536 + r) * SD + t] = src[t];
  if (t == 0) a.bpk[cd * 1536 + r] = (r < 768) ? a.bA[cd][r] : a.bB[cd][r - 768];
}

// Pack transposed step-gate weights: Wt[cd][kb][row][4] = W[row][kb*4+k3],
// rows 0..767 = cwhh, 768..1535 = pwih.  Grid (64 kb, 4 cd).
struct PTArgs { const float* wc[4]; const float* wp[4]; float* Wt; };
__global__ void packT_k(PTArgs a)
{
  const int kb = blockIdx.x, cd = blockIdx.y, t = threadIdx.x;
#pragma unroll
  for (int p = 0; p < 6; ++p) {
    const int r = t + 256 * p;
    const float* src = (r < 768) ? (a.wc[cd] + (long)r * SD)
                                 : (a.wp[cd] + (long)(r - 768) * SD);
    const float4 v = *(const float4*)(src + kb * 4);
    *(float4*)(a.Wt + (((size_t)cd * 64 + kb) * 1536 + r) * 4) = v;
  }
}

// S0[m] = Q[m,:] . bk
__global__ void s0_k(const float* __restrict__ Q, const float* __restrict__ bk,
                     float* __restrict__ S0)
{
  const int r = blockIdx.x * 4 + (threadIdx.x >> 6), lane = threadIdx.x & 63;
  const float4 q  = *(const float4*)(Q + (long)r * SD + lane * 4);
  const float4 kb = *(const float4*)(bk + lane * 4);
  float p = q.x*kb.x + q.y*kb.y + q.z*kb.z + q.w*kb.w;
  p = wsum(p);
  if (lane == 0) S0[r] = p;
}

// ---------------------------------------------------------------------------
// Chunk step kernel: runs CS sequential DAG steps in one launch.
// 64 blocks = 4 cd (cd = blk&3, spreads each cd onto 2 XCDs for L2 weight
// locality) x 16 b-groups. Each WAVE owns one (cd,b) chain: attention (M in
// LDS) + full 1536-row gate dot + GRU elementwise + H1-row write. No
// __syncthreads, no inter-block communication; H1 rows of b are written and
// read only by b's wave (cross-step same-wave RAW fenced by
// __threadfence_block).
// ---------------------------------------------------------------------------
struct StepArgs {
  const float* Qt[4]; const float* S0[4];
  const int* adj[4]; int rev[4];
  const float* bc[4]; const float* bp[4];   // cbhh, pbih
  const float* GK[4]; const float* X[4];
  float* H1[4];                             // time-major stride SD2, col-offset baked
  const float* Wt;                          // packed transposed [cd][64][1536][4]
  int ldX, s0;
};
__global__ __launch_bounds__(256) void step_chunk_k(StepArgs a)
{
  __shared__ float Mlds[4][256];
  __shared__ float lg[4][128];
  __shared__ float wgt[4][128];
  __shared__ float adjm[4][128];
  const int blk = blockIdx.x;
  const int cd = blk & 3, bg = blk >> 2;
  const int t = threadIdx.x, w = t >> 6, l = t & 63;
  const int b = bg * 4 + w;
  const float* Qtp  = a.Qt[cd];
  const float* S0p  = a.S0[cd];
  const int*   adjp = a.adj[cd];
  const int    rev  = a.rev[cd];
  const float* WtC  = a.Wt + (size_t)cd * (64 * 1536 * 4);
  const float* gkB  = a.GK[cd];
  const float* Xp   = a.X[cd];
  float* H1 = a.H1[cd];
  // hoist biases (constant over steps): index j = l + 64c, gate g
  float bcv[12], bpv[12];
#pragma unroll
  for (int g = 0; g < 3; ++g)
#pragma unroll
    for (int c = 0; c < 4; ++c) {
      bcv[g*4+c] = a.bc[cd][g*SD + l + 64*c];
      bpv[g*4+c] = a.bp[cd][g*SD + l + 64*c];
    }

  for (int i = a.s0; i < a.s0 + CS; ++i) {
    // ---- attention -> M (per-wave) ----
    if (i == 0) {
      const float4 z = {0.f, 0.f, 0.f, 0.f};
      *(float4*)&Mlds[w][l*4] = z;
    } else {
      const float4 q4 = *(const float4*)(Qtp + ((long)i*64 + b)*SD + l*4);
      const float s0v = S0p[i*64 + b];
      const int ii = rev ? (SN-1-i) : i;
      {
        const int nn0 = rev ? (SN-1-l) : l;
        const int nn1 = rev ? (63-l)   : (l+64);
        adjm[w][l]    = (float)adjp[((long)b*SN + ii)*SN + nn0];
        adjm[w][l+64] = (float)adjp[((long)b*SN + ii)*SN + nn1];
      }
      for (int n = 0; n < i; ++n) {
        const float4 h4 = *(const float4*)(H1 + ((long)n*64 + b)*SD2 + l*4);
        float p = q4.x*h4.x + q4.y*h4.y + q4.z*h4.z + q4.w*h4.w;
        p = wsum(p);
        if (l == 0) lg[w][n] = p;
      }
      const float v0 = (l < i)    ? (lg[w][l]    + s0v - (1.f - adjm[w][l]   )*1e30f) : -3.0e38f;
      const float v1 = (l+64 < i) ? (lg[w][l+64] + s0v - (1.f - adjm[w][l+64])*1e30f) : -3.0e38f;
      float mx = fmaxf(v0, v1);
#pragma unroll
      for (int o = 32; o; o >>= 1) mx = fmaxf(mx, __shfl_xor(mx, o));
      const float e0 = (l < i)    ? expf(v0 - mx) : 0.f;
      const float e1 = (l+64 < i) ? expf(v1 - mx) : 0.f;
      float sum = e0 + e1;
#pragma unroll
      for (int o = 32; o; o >>= 1) sum += __shfl_xor(sum, o);
      const float inv = 1.f / sum;
      if (l < i)    wgt[w][l]    = e0 * inv;
      if (l+64 < i) wgt[w][l+64] = e1 * inv;
      float4 acc4 = {0.f, 0.f, 0.f, 0.f};
      for (int n = 0; n < i; ++n) {
        const float4 h4 = *(const float4*)(H1 + ((long)n*64 + b)*SD2 + l*4);
        const float wn = wgt[w][n];
        acc4.x = fmaf(wn, h4.x, acc4.x);
        acc4.y = fmaf(wn, h4.y, acc4.y);
        acc4.z = fmaf(wn, h4.z, acc4.z);
        acc4.w = fmaf(wn, h4.w, acc4.w);
      }
      *(float4*)&Mlds[w][l*4] = acc4;
    }
    // ---- gates: acc[m] = sum_k Wt[row=l+64m][k] * M[k] ----
    float acc[24];
#pragma unroll
    for (int m = 0; m < 24; ++m) acc[m] = 0.f;
    {
      const float* wp0 = WtC + (size_t)l * 4;
      for (int kb = 0; kb < 64; ++kb) {
        const float4 m4 = *(const float4*)&Mlds[w][kb*4];
        const float* wr = wp0 + (size_t)kb * (1536*4);
#pragma unroll
        for (int m = 0; m < 24; ++m) {
          const float4 w4 = *(const float4*)(wr + m * 256);
          acc[m] = fmaf(w4.x, m4.x, acc[m]);
          acc[m] = fmaf(w4.y, m4.y, acc[m]);
          acc[m] = fmaf(w4.z, m4.z, acc[m]);
          acc[m] = fmaf(w4.w, m4.w, acc[m]);
        }
      }
    }
    // ---- GRU elementwise + H1-row write ----
    const long rowT = (long)i*64 + b;
    const float* gk = gkB + ((long)(i - a.s0)*64 + b) * 1536;
    const float* xr = Xp + rowT * a.ldX;
    float* hout = H1 + rowT * SD2;
#pragma unroll
    for (int c = 0; c < 4; ++c) {
      const int j = l + 64*c;
      const float ghc_r = acc[c]    + bcv[c];
      const float ghc_z = acc[4+c]  + bcv[4+c];
      const float ghc_n = acc[8+c]  + bcv[8+c];
      const float gip_r = acc[12+c] + bpv[c];
      const float gip_z = acc[16+c] + bpv[4+c];
      const float gip_n = acc[20+c] + bpv[8+c];
      const float gic_r = gk[j],      gic_z = gk[SD+j],   gic_n = gk[2*SD+j];
      const float ghp_r = gk[3*SD+j], ghp_z = gk[4*SD+j], ghp_n = gk[5*SD+j];
      const float xj = xr[j];
      const float mj = Mlds[w][j];
      const float rC = sigm(gic_r + ghc_r);
      const float zC = sigm(gic_z + ghc_z);
      const float nC = tanhf(gic_n + rC * ghc_n);
      const float Cc = (1.f - zC) * nC + zC * mj;
      const float rP = sigm(gip_r + ghp_r);
      const float zP = sigm(gip_z + ghp_z);
      const float nP = tanhf(gip_n + rP * ghp_n);
      hout[j] = Cc + (1.f - zP) * nP + zP * xj;
    }
    __threadfence_block();   // order H1 stores before next step's loads
  }
}

__global__ void zero_k(float* p, long n)
{
  for (long idx = (long)blockIdx.x * 256 + threadIdx.x; idx < n; idx += (long)gridDim.x * 256)
    p[idx] = 0.f;
}

// column means of (8192 x 512), grid (8 colblocks, 32 rowslices), atomicAdd
__global__ void colmean_k(const float* __restrict__ X, float* __restrict__ mean)
{
  __shared__ float red[256];
  const int c = blockIdx.x * 64 + (threadIdx.x & 63), rq = threadIdx.x >> 6;
  const int r0 = blockIdx.y * 256;
  float acc = 0.f;
  for (int r = r0 + rq; r < r0 + 256; r += 4) acc += X[(long)r * SD2 + c];
  red[threadIdx.x] = acc;
  __syncthreads();
  if (threadIdx.x < 64) {
    const float s = red[threadIdx.x] + red[64 + threadIdx.x] + red[128 + threadIdx.x] + red[192 + threadIdx.x];
    atomicAdd(&mean[c], s * (1.f / 8192.f));
  }
}

__global__ void rownorm_k(const float* __restrict__ X, const float* __restrict__ mean,
                          float* __restrict__ inv)
{
  const int r = blockIdx.x * 4 + (threadIdx.x >> 6), lane = threadIdx.x & 63;
  const float* xp = X + (long)r * SD2 + lane * 8;
  const float4 v0 = *(const float4*)xp;
  const float4 v1 = *(const float4*)(xp + 4);
  const float4 m0 = *(const float4*)(mean + lane * 8);
  const float4 m1 = *(const float4*)(mean + lane * 8 + 4);
  float ss = 0.f, d;
  d = v0.x - m0.x; ss += d*d;  d = v0.y - m0.y; ss += d*d;
  d = v0.z - m0.z; ss += d*d;  d = v0.w - m0.w; ss += d*d;
  d = v1.x - m1.x; ss += d*d;  d = v1.y - m1.y; ss += d*d;
  d = v1.z - m1.z; ss += d*d;  d = v1.w - m1.w; ss += d*d;
  ss = wsum(ss);
  if (lane == 0) inv[r] = 1.f / (sqrtf(ss) + 1e-6f);
}

// partial G += xhat^T yhat over K slice; grid (8, 8, 16)
__global__ __launch_bounds__(256)
void gpart_k(const float* __restrict__ X, const float* __restrict__ Y,
             const float* __restrict__ mx, const float* __restrict__ my,
             const float* __restrict__ ix, const float* __restrict__ iy,
             float* __restrict__ G)
{
  __shared__ float As[16][68];
  __shared__ float Bs[16][68];
  __shared__ float mxs[64], mys[64];
  const int t = threadIdx.x, tx = t & 15, ty = t >> 4;
  const int ci = blockIdx.y * 64, cj = blockIdx.x * 64;
  if (t < 64) { mxs[t] = mx[ci + t]; mys[t] = my[cj + t]; }
  float acc[4][4];
#pragma unroll
  for (int ii = 0; ii < 4; ++ii)
#pragma unroll
    for (int jj = 0; jj < 4; ++jj) acc[ii][jj] = 0.f;
  const int rl = t >> 4, c4 = (t & 15) * 4;
  __syncthreads();
  const int kend = blockIdx.z * 512 + 512;
  for (int kb = blockIdx.z * 512; kb < kend; kb += 16) {
    const int r = kb + rl;
    const float4 xv = *(const float4*)(X + (long)r * SD2 + ci + c4);
    const float4 yv = *(const float4*)(Y + (long)r * SD2 + cj + c4);
    const float vx = ix[r], vy = iy[r];
    __syncthreads();
    As[rl][c4+0] = (xv.x - mxs[c4+0]) * vx; As[rl][c4+1] = (xv.y - mxs[c4+1]) * vx;
    As[rl][c4+2] = (xv.z - mxs[c4+2]) * vx; As[rl][c4+3] = (xv.w - mxs[c4+3]) * vx;
    Bs[rl][c4+0] = (yv.x - mys[c4+0]) * vy; Bs[rl][c4+1] = (yv.y - mys[c4+1]) * vy;
    Bs[rl][c4+2] = (yv.z - mys[c4+2]) * vy; Bs[rl][c4+3] = (yv.w - mys[c4+3]) * vy;
    __syncthreads();
#pragma unroll
    for (int kk = 0; kk < 16; ++kk) {
      float av[4], bv[4];
      *(float4*)&av[0] = *(const float4*)&As[kk][ty*4];
      *(float4*)&bv[0] = *(const float4*)&Bs[kk][tx*4];
#pragma unroll
      for (int ii = 0; ii < 4; ++ii)
#pragma unroll
        for (int jj = 0; jj < 4; ++jj)
          acc[ii][jj] = fmaf(av[ii], bv[jj], acc[ii][jj]);
    }
  }
#pragma unroll
  for (int ii = 0; ii < 4; ++ii)
#pragma unroll
    for (int jj = 0; jj < 4; ++jj)
      atomicAdd(&G[(long)(ci + ty*4 + ii) * SD2 + cj + tx*4 + jj], acc[ii][jj]);
}

__global__ void sqsum_k(const float* __restrict__ G, float* __restrict__ dl)
{
  __shared__ float red[4];
  float s = 0.f;
  const long base = (long)blockIdx.x * 1024;
#pragma unroll
  for (int it = 0; it < 4; ++it) { const float v = G[base + it*256 + threadIdx.x]; s += v*v; }
  s = wsum(s);
  const int lane = threadIdx.x & 63, wv = threadIdx.x >> 6;
  if (lane == 0) red[wv] = s;
  __syncthreads();
  if (threadIdx.x == 0) atomicAdd(dl, red[0] + red[1] + red[2] + red[3]);
}

// softmax over rows of length 128 (in-place)
__global__ void smax_k(float* __restrict__ S)
{
  const int r = blockIdx.x * 4 + (threadIdx.x >> 6), lane = threadIdx.x & 63;
  float* p = S + (long)r * SN;
  const float v0 = p[lane], v1 = p[lane + 64];
  float mx = fmaxf(v0, v1);
#pragma unroll
  for (int o = 32; o; o >>= 1) mx = fmaxf(mx, __shfl_xor(mx, o));
  const float e0 = expf(v0 - mx), e1 = expf(v1 - mx);
  float s = e0 + e1;
#pragma unroll
  for (int o = 32; o; o >>= 1) s += __shfl_xor(s, o);
  const float inv = 1.f / s;
  p[lane] = e0 * inv; p[lane + 64] = e1 * inv;
}

__global__ void head_k(const float* __restrict__ H, const float* __restrict__ W,
                       const float* __restrict__ bo, float* __restrict__ out)
{
  const int r = blockIdx.x * 4 + (threadIdx.x >> 6), lane = threadIdx.x & 63;
  const float4 h = *(const float4*)(H + (long)r * SD + lane * 4);
#pragma unroll
  for (int c = 0; c < SNC; ++c) {
    const float4 w = *(const float4*)(W + (long)c * SD + lane * 4);
    float p = h.x*w.x + h.y*w.y + h.z*w.z + h.w*w.w;
    p = wsum(p);
    if (lane == 0) out[(long)r * SNC + c] = p + bo[c];
  }
}

__global__ void fin_k(const float* __restrict__ dl, float* __restrict__ out)
{
  out[0] = (dl[0] + dl[1]) * (0.3f / (512.f * 512.f));
}

// ---------------------------------------------------------------------------
extern "C" void kernel_launch(void* const* d_in, const int* in_sizes, int n_in,
                              void* d_out, int out_size, void* d_ws, size_t ws_size,
                              hipStream_t stream)
{
  (void)in_sizes; (void)n_in; (void)out_size; (void)ws_size;
  const float* F    = (const float*)d_in[0];
  const int*   adj1 = (const int*)  d_in[1];
  const int*   adj2 = (const int*)  d_in[2];
  const float* fc1w = (const float*)d_in[6];
  const float* fc1b = (const float*)d_in[7];
  const float *g_wih[4], *g_whh[4], *g_bih[4], *g_bhh[4];  // gcs, gps, gcl, gpl
  for (int g = 0; g < 4; ++g) {
    g_wih[g] = (const float*)d_in[8 + g*4 + 0];
    g_whh[g] = (const float*)d_in[8 + g*4 + 1];
    g_bih[g] = (const float*)d_in[8 + g*4 + 2];
    g_bhh[g] = (const float*)d_in[8 + g*4 + 3];
  }
  const float* gat_wq[2] = {(const float*)d_in[24], (const float*)d_in[28]};
  const float* gat_bq[2] = {(const float*)d_in[25], (const float*)d_in[29]};
  const float* gat_wk[2] = {(const float*)d_in[26], (const float*)d_in[30]};
  const float* gat_bk[2] = {(const float*)d_in[27], (const float*)d_in[31]};
  const float* aff1 = (const float*)d_in[32];
  const float* aff2 = (const float*)d_in[33];
  const float* mw1  = (const float*)d_in[34];
  const float* mb1  = (const float*)d_in[35];
  const float* mw2  = (const float*)d_in[36];
  const float* mb2  = (const float*)d_in[37];
  const float* ow   = (const float*)d_in[38];
  const float* ob   = (const float*)d_in[39];
  float* out = (float*)d_out;

  // ---- workspace layout ----
  float* ws = (float*)d_ws;
  size_t off = 0;
  auto take = [&](size_t nf){ float* p = ws + off; off += nf; return p; };
  float* region = take(22552576);           // overlay region
  float* X0f  = region;                     // 2,097,152 (time-major layer-0 fwd)
  float* X0r  = region + 2097152;           // 2,097,152 (time-major layer-0 bwd)
  float* Qtb  = region + 4194304;           // 4 x 2,097,152
  float* Qtmp = region + 12582912;          // 2,097,152
  float* GKC  = region + 14680064;          // 4 x 1,572,864 (chunk gate precompute)
  float* Htmp = GKC;                        // alias: b-major H0 temp (early only)
  float* Wpk  = region + 20971520;          // 1,572,864
  float* bpk  = region + 22544384;          // 6,144 (+pad)
  // finals overlay (sequential-phase buffers dead by then)
  float* T  = region;                       // 4,194,304
  float* Sb = region + 4194304;             // 1,048,576
  float* HH = region + 5242880;             // 4,194,304
  float* h1 = region + 9437184;             // 2,097,152
  float* h2 = region + 11534336;            // 2,097,152
  float* Ocat[2][2];                        // time-major H1 storage, stride 512
  for (int c = 0; c < 2; ++c) for (int l = 0; l < 2; ++l) Ocat[c][l] = take(4194304);
  float* S0b   = take(32768);               // 4 x 8192
  float* WtB   = take(1572864);             // 4 cd x [64][1536][4] transposed step weights
  float* meanx = take(512);
  float* meany = take(512);
  float* invx  = take(8192);
  float* invy  = take(8192);
  float* dl    = take(8);
  float* Gbuf  = take(262144);

  // H0 = relu(F @ fc1w^T + fc1b)  (b-major temp), then spread to time-major
  gemm_k<false,true,true,false><<<dim3(4,64,1),256,0,stream>>>(
      F, fc1w, fc1b, Htmp, SD, SE, SE, SE, SD, 0,0,0);
  spread_k<<<SBN,256,0,stream>>>(Htmp, X0f, X0r);

  for (int l = 0; l < 2; ++l) {
    PkArgs pk; PTArgs pt; StepArgs sta;
    sta.ldX = l ? SD2 : SD;
    sta.Wt = WtB;
    const float* Xarr[4]; const int ldX = sta.ldX;
    for (int cd = 0; cd < 4; ++cd) {
      const int ch = cd >> 1;  // 0 = s-channel, 1 = l-channel
      const float* X = (l == 0) ? ((cd & 1) ? X0r : X0f)
                                : (Ocat[ch][0] + (cd & 1) * SD);
      Xarr[cd] = X;
      const float* wq   = gat_wq[ch] + l * SD * SD;
      const float* bq   = gat_bq[ch] + l * SD;
      const float* wk   = gat_wk[ch] + l * SD * SD;
      const float* bk   = gat_bk[ch] + l * SD;
      const float* cwih = g_wih[ch*2+0] + l * SD3 * SD;
      const float* cwhh = g_whh[ch*2+0] + l * SD3 * SD;
      const float* cbih = g_bih[ch*2+0] + l * SD3;
      const float* cbhh = g_bhh[ch*2+0] + l * SD3;
      const float* pwih = g_wih[ch*2+1] + l * SD3 * SD;
      const float* pwhh = g_whh[ch*2+1] + l * SD3 * SD;
      const float* pbih = g_bih[ch*2+1] + l * SD3;
      const float* pbhh = g_bhh[ch*2+1] + l * SD3;
      pk.wA[cd] = cwih; pk.wB[cd] = pwhh; pk.bA[cd] = cbih; pk.bB[cd] = pbhh;
      pt.wc[cd] = cwhh; pt.wp[cd] = pwih;
      // Qtmp = X@wq^T + bq ; Qt = Qtmp@wk ; S0 = Qtmp . bk
      gemm_k<false,true,false,false><<<dim3(4,64,1),256,0,stream>>>(
          X, wq, bq, Qtmp, SD, SD, ldX, SD, SD, 0,0,0);
      gemm_k<true,false,false,false><<<dim3(4,64,1),256,0,stream>>>(
          Qtmp, wk, nullptr, Qtb + (size_t)cd*2097152, SD, SD, SD, SD, SD, 0,0,0);
      s0_k<<<SBN/4,256,0,stream>>>(Qtmp, bk, S0b + cd*SBN);
      float* H1mut = Ocat[ch][l] + (cd & 1) * SD;
      sta.Qt[cd] = Qtb + (size_t)cd*2097152;
      sta.S0[cd] = S0b + cd*SBN;
      sta.H1[cd] = H1mut;
      sta.adj[cd] = ch ? adj2 : adj1; sta.rev[cd] = cd & 1;
      sta.bc[cd] = cbhh; sta.bp[cd] = pbih;
      sta.GK[cd] = GKC + (size_t)cd*1572864;
      sta.X[cd] = X;
    }
    pk.Wpk = Wpk; pk.bpk = bpk;
    pack_k<<<dim3(1536,4),256,0,stream>>>(pk);
    pt.Wt = WtB;
    packT_k<<<dim3(64,4),256,0,stream>>>(pt);

    for (int s0 = 0; s0 < SN; s0 += CS) {
      // gate precompute for chunk: GKC[cd] = X[rows s0*64 .. +1024) @ Wpk^T + bpk
      for (int cd = 0; cd < 4; ++cd)
        gemm_k<false,true,false,false><<<dim3(24,8,1),256,0,stream>>>(
            Xarr[cd] + (long)s0*64*ldX, Wpk + (size_t)cd*1536*SD, bpk + cd*1536,
            GKC + (size_t)cd*1572864, 1536, SD, ldX, SD, 1536, 0,0,0);
      sta.s0 = s0;
      step_chunk_k<<<64,256,0,stream>>>(sta);
    }
  }

  // diff loss (row-permutation invariant -> time-major OK)
  zero_k<<<1,256,0,stream>>>(dl, 2);
  for (int l = 0; l < 2; ++l) {
    zero_k<<<4,256,0,stream>>>(meanx, 1024);  // meanx+meany contiguous
    colmean_k<<<dim3(8,32,1),256,0,stream>>>(Ocat[0][l], meanx);
    colmean_k<<<dim3(8,32,1),256,0,stream>>>(Ocat[1][l], meany);
    rownorm_k<<<SBN/4,256,0,stream>>>(Ocat[0][l], meanx, invx);
    rownorm_k<<<SBN/4,256,0,stream>>>(Ocat[1][l], meany, invy);
    zero_k<<<256,256,0,stream>>>(Gbuf, (long)SD2*SD2);
    gpart_k<<<dim3(8,8,16),256,0,stream>>>(Ocat[0][l], Ocat[1][l], meanx, meany, invx, invy, Gbuf);
    sqsum_k<<<256,256,0,stream>>>(Gbuf, dl + l);
  }

  // cross attention + final MLP (h1 accumulated from F / HSn / HLn slices)
  gemm_k<true,false,false,false><<<dim3(8,64,1),256,0,stream>>>(
      Ocat[0][1], aff1, nullptr, T, SD2, SD2, SD2, SD2, SD2, 0,0,0);
  gemm_k<false,false,false,false><<<dim3(2,1,64),256,0,stream>>>(
      T, Ocat[1][1], nullptr, Sb, SN, SD2, 64*SD2, 64*SD2, SN, SD2, SD2, (long)SN*SN);
  smax_k<<<SBN/4,256,0,stream>>>(Sb);
  gemm_k<true,false,false,false><<<dim3(8,1,64),256,0,stream>>>(
      Sb, Ocat[1][1], nullptr, HH, SD2, SN, SN, 64*SD2, SD2, (long)SN*SN, SD2, (long)SN*SD2);
  gemm_k<false,true,false,false><<<dim3(4,64,1),256,0,stream>>>(
      F, mw1, mb1, h1, SD, SE, SE, SIN, SD, 0,0,0);
  gemm_k<false,false,false,true><<<dim3(4,64,1),256,0,stream>>>(
      HH, mw1 + 1024, nullptr, h1, SD, SD2, SD2, SIN, SD, 0,0,0);
  gemm_k<true,false,false,false><<<dim3(8,64,1),256,0,stream>>>(
      Ocat[1][1], aff2, nullptr, T, SD2, SD2, SD2, SD2, SD2, 0,0,0);
  gemm_k<false,false,false,false><<<dim3(2,1,64),256,0,stream>>>(
      T, Ocat[0][1], nullptr, Sb, SN, SD2, 64*SD2, 64*SD2, SN, SD2, SD2, (long)SN*SN);
  smax_k<<<SBN/4,256,0,stream>>>(Sb);
  gemm_k<true,false,false,false><<<dim3(8,1,64),256,0,stream>>>(
      Sb, Ocat[0][1], nullptr, HH, SD2, SN, SN, 64*SD2, SD2, (long)SN*SN, SD2, (long)SN*SD2);
  gemm_k<false,false,true,true><<<dim3(4,64,1),256,0,stream>>>(
      HH, mw1 + 1536, nullptr, h1, SD, SD2, SD2, SIN, SD, 0,0,0);
  gemm_k<false,true,true,false><<<dim3(4,64,1),256,0,stream>>>(
      h1, mw2, mb2, h2, SD, SD, SD, SD, SD, 0,0,0);
  head_k<<<SBN/4,256,0,stream>>>(h2, ow, ob, out);
  fin_k<<<1,1,0,stream>>>(dl, out + SBN * SNC);
}

// Round 6
// 9412.499 us; speedup vs baseline: 4.7712x; 4.7712x over previous
//
#include <hip/hip_runtime.h>
#include <math.h>

// Problem constants
#define SB   64     // batch
#define SN   128    // seq len
#define SE   1024   // feature dim
#define SD   256    // hidden D
#define SD2  512    // 2D
#define SD3  768    // 3D
#define SIN  2048   // 4D+E
#define SNC  7
#define SBN  8192   // SB*SN
#define CS   8      // chunk steps (GK tile held in LDS)

__device__ __forceinline__ float wsum(float v){
#pragma unroll
  for (int o = 32; o; o >>= 1) v += __shfl_xor(v, o);
  return v;
}
__device__ __forceinline__ float sigm(float x){ return 1.f/(1.f + expf(-x)); }

// ---------------------------------------------------------------------------
// Generic fp32 GEMM: C[M,N] = A @ op(B) (+bias)(+acc)(+relu), batched via z.
// BKMAJ=false: B rows are N (NT).  BKMAJ=true: B rows are K (NN).
// BM=128, BN=64, BK=16, 256 threads, 8x4 micro-tile.
// ---------------------------------------------------------------------------
template<bool BKMAJ, bool BIAS, bool RELU, bool ACC>
__global__ __launch_bounds__(256)
void gemm_k(const float* __restrict__ A, const float* __restrict__ Bm,
            const float* __restrict__ bias, float* __restrict__ C,
            int Nn, int K, int lda, int ldb, int ldc,
            long sA, long sB, long sC)
{
  __shared__ float As[16][132];
  __shared__ float Bs[16][68];
  const int t  = threadIdx.x;
  const int tx = t & 15, ty = t >> 4;
  const float* Ab = A + (long)blockIdx.z * sA;
  const float* Bb = Bm + (long)blockIdx.z * sB;
  float* Cb = C + (long)blockIdx.z * sC;
  const int m0 = blockIdx.y * 128, n0 = blockIdx.x * 64;
  float acc[8][4];
#pragma unroll
  for (int i = 0; i < 8; ++i)
#pragma unroll
    for (int j = 0; j < 4; ++j) acc[i][j] = 0.f;

  const int am = t >> 1, ak = (t & 1) * 8;
  int bn_ = 0, bk_ = 0;
  if (BKMAJ) { bk_ = t >> 4; bn_ = (t & 15) * 4; }
  else       { bn_ = t >> 2; bk_ = (t & 3) * 4; }

  for (int k0 = 0; k0 < K; k0 += 16) {
    const float4 a0 = *(const float4*)(Ab + (long)(m0 + am) * lda + k0 + ak);
    const float4 a1 = *(const float4*)(Ab + (long)(m0 + am) * lda + k0 + ak + 4);
    float4 b0;
    if (BKMAJ) b0 = *(const float4*)(Bb + (long)(k0 + bk_) * ldb + n0 + bn_);
    else       b0 = *(const float4*)(Bb + (long)(n0 + bn_) * ldb + k0 + bk_);
    __syncthreads();
    As[ak+0][am] = a0.x; As[ak+1][am] = a0.y; As[ak+2][am] = a0.z; As[ak+3][am] = a0.w;
    As[ak+4][am] = a1.x; As[ak+5][am] = a1.y; As[ak+6][am] = a1.z; As[ak+7][am] = a1.w;
    if (BKMAJ) { *(float4*)&Bs[bk_][bn_] = b0; }
    else { Bs[bk_+0][bn_] = b0.x; Bs[bk_+1][bn_] = b0.y; Bs[bk_+2][bn_] = b0.z; Bs[bk_+3][bn_] = b0.w; }
    __syncthreads();
#pragma unroll
    for (int kk = 0; kk < 16; ++kk) {
      float av[8], bv[4];
      *(float4*)&av[0] = *(const float4*)&As[kk][ty*8];
      *(float4*)&av[4] = *(const float4*)&As[kk][ty*8+4];
      *(float4*)&bv[0] = *(const float4*)&Bs[kk][tx*4];
#pragma unroll
      for (int ii = 0; ii < 8; ++ii)
#pragma unroll
        for (int jj = 0; jj < 4; ++jj)
          acc[ii][jj] = fmaf(av[ii], bv[jj], acc[ii][jj]);
    }
  }
#pragma unroll
  for (int ii = 0; ii < 8; ++ii) {
#pragma unroll
    for (int jj = 0; jj < 4; ++jj) {
      float v = acc[ii][jj];
      if (BIAS) v += bias[n0 + tx*4 + jj];
      const long ci = (long)(m0 + ty*8 + ii) * ldc + n0 + tx*4 + jj;
      if (ACC) v += Cb[ci];
      if (RELU) v = fmaxf(v, 0.f);
      Cb[ci] = v;
    }
  }
}

// Htmp is b-major (row b*128+n). Write time-major X0f[(n*64+b)] and reversed.
__global__ void spread_k(const float* __restrict__ src, float* __restrict__ xf,
                         float* __restrict__ xr)
{
  const int r = blockIdx.x, t = threadIdx.x;   // src row = b*128+n
  const int b = r >> 7, n = r & 127;
  const float v = src[(long)r * SD + t];
  xf[((long)(n * 64 + b)) * SD + t] = v;
  xr[((long)((127 - n) * 64 + b)) * SD + t] = v;
}

// Pack transposed weights: Wt[cd][kb][row][4] = W[row][kb*4+k3],
// rows 0..767 from wc, 768..1535 from wp.  Grid (64 kb, 4 cd).
struct PTArgs { const float* wc[4]; const float* wp[4]; float* Wt; };
__global__ void packT_k(PTArgs a)
{
  const int kb = blockIdx.x, cd = blockIdx.y, t = threadIdx.x;
#pragma unroll
  for (int p = 0; p < 6; ++p) {
    const int r = t + 256 * p;
    const float* src = (r < 768) ? (a.wc[cd] + (long)r * SD)
                                 : (a.wp[cd] + (long)(r - 768) * SD);
    const float4 v = *(const float4*)(src + kb * 4);
    *(float4*)(a.Wt + (((size_t)cd * 64 + kb) * 1536 + r) * 4) = v;
  }
}

// S0[m] = Q[m,:] . bk
__global__ void s0_k(const float* __restrict__ Q, const float* __restrict__ bk,
                     float* __restrict__ S0)
{
  const int r = blockIdx.x * 4 + (threadIdx.x >> 6), lane = threadIdx.x & 63;
  const float4 q  = *(const float4*)(Q + (long)r * SD + lane * 4);
  const float4 kb = *(const float4*)(bk + lane * 4);
  float p = q.x*kb.x + q.y*kb.y + q.z*kb.z + q.w*kb.w;
  p = wsum(p);
  if (lane == 0) S0[r] = p;
}

// ---------------------------------------------------------------------------
// Chunk step kernel: CS sequential DAG steps in one launch.
// 256 blocks = one BLOCK per (cd, b) chain; cd = blk & 3 pins each cd's
// weight stream to 2 XCDs' L2. Per chunk: GK phase (gate-input precompute
// for CS steps into LDS, weights streamed coalesced via k-packed layout),
// then CS x (attention -> M in LDS -> 1536-row gate dot (6 rows/thread)
// -> GRU -> H1 row write). No inter-block communication at all.
// ---------------------------------------------------------------------------
struct StepArgs {
  const float* Qt[4]; const float* S0[4];
  const int* adj[4]; int rev[4];
  const float* bc[4];  const float* bp[4];   // cbhh, pbih (step-gate biases)
  const float* bgc[4]; const float* bgp[4];  // cbih, pbhh (GK biases)
  const float* X[4];
  float* H1[4];                              // time-major stride SD2, col-offset baked
  const float* Wt;   // [cd][64][1536][4]: rows 0..767 cwhh, 768..1535 pwih
  const float* Wgk;  // [cd][64][1536][4]: rows 0..767 cwih, 768..1535 pwhh
  int ldX, s0;
};
__global__ __launch_bounds__(256, 1) void step_chunk_k(StepArgs a)
{
  __shared__ float smem[14976];   // 59.9 KB
  float* GKs  = smem;             // [CS][1536]
  float* Xs   = smem + 12288;     // [CS][256]
  float* Mlds = smem + 14336;     // [256]
  float* lg   = smem + 14592;     // [128]
  float* wgt  = smem + 14720;     // [128]
  float* adjm = smem + 14848;     // [128]

  const int blk = blockIdx.x;
  const int cd = blk & 3, b = blk >> 2;
  const int t = threadIdx.x, q = t >> 6, l = t & 63;
  const int j = t;                        // output column 0..255
  const int ldX = a.ldX, s0 = a.s0;
  const float* Xp  = a.X[cd];
  float* H1 = a.H1[cd];
  const float* Qtp = a.Qt[cd];
  const float* S0p = a.S0[cd];
  const int*   adjp = a.adj[cd];
  const int    rev  = a.rev[cd];

  // hoisted biases for this thread's column j
  const float bc0 = a.bc[cd][j],  bc1 = a.bc[cd][256+j],  bc2 = a.bc[cd][512+j];
  const float bp0 = a.bp[cd][j],  bp1 = a.bp[cd][256+j],  bp2 = a.bp[cd][512+j];

  // ---- GK phase: GKs[s][g*256+j] = X[s0+s,b] . Wgk_row(g*256+j) + bias ----
#pragma unroll
  for (int s = 0; s < CS; ++s)
    Xs[s*256 + t] = Xp[((long)(s0+s)*64 + b)*ldX + t];
  __syncthreads();
  {
    float gacc[6][CS];
#pragma unroll
    for (int g = 0; g < 6; ++g)
#pragma unroll
      for (int s = 0; s < CS; ++s) gacc[g][s] = 0.f;
    const float* wbase = a.Wgk + ((size_t)cd*64*1536 + j)*4;
    for (int kb = 0; kb < 64; ++kb) {
      const float* wr = wbase + (size_t)kb*6144;
      float4 w[6];
#pragma unroll
      for (int g = 0; g < 6; ++g) w[g] = *(const float4*)(wr + g*1024);
#pragma unroll
      for (int s = 0; s < CS; ++s) {
        const float4 x4 = *(const float4*)&Xs[s*256 + kb*4];
#pragma unroll
        for (int g = 0; g < 6; ++g) {
          gacc[g][s] = fmaf(w[g].x, x4.x, gacc[g][s]);
          gacc[g][s] = fmaf(w[g].y, x4.y, gacc[g][s]);
          gacc[g][s] = fmaf(w[g].z, x4.z, gacc[g][s]);
          gacc[g][s] = fmaf(w[g].w, x4.w, gacc[g][s]);
        }
      }
    }
#pragma unroll
    for (int g = 0; g < 6; ++g) {
      const float bg = (g < 3) ? a.bgc[cd][g*256 + j] : a.bgp[cd][(g-3)*256 + j];
#pragma unroll
      for (int s = 0; s < CS; ++s)
        GKs[s*1536 + g*256 + j] = gacc[g][s] + bg;
    }
  }
  __syncthreads();

  // ---- CS sequential steps ----
  for (int i = s0; i < s0 + CS; ++i) {
    if (i == 0) {
      Mlds[t] = 0.f;
      __syncthreads();
    } else {
      if (t < 128) {
        const int ii = rev ? (SN-1-i) : i;
        const int nn = rev ? (SN-1-t) : t;
        adjm[t] = (float)adjp[((long)b*SN + ii)*SN + nn];
      }
      const float4 q4 = *(const float4*)(Qtp + ((long)i*64 + b)*SD + l*4);
      for (int n = q; n < i; n += 4) {
        const float4 h4 = *(const float4*)(H1 + ((long)n*64 + b)*SD2 + l*4);
        float p = q4.x*h4.x + q4.y*h4.y + q4.z*h4.z + q4.w*h4.w;
        p = wsum(p);
        if (l == 0) lg[n] = p;
      }
      __syncthreads();
      if (q == 0) {
        const float s0v = S0p[i*64 + b];
        const float v0 = (l < i)    ? (lg[l]    + s0v - (1.f - adjm[l]   )*1e30f) : -3.0e38f;
        const float v1 = (l+64 < i) ? (lg[l+64] + s0v - (1.f - adjm[l+64])*1e30f) : -3.0e38f;
        float mx = fmaxf(v0, v1);
#pragma unroll
        for (int o = 32; o; o >>= 1) mx = fmaxf(mx, __shfl_xor(mx, o));
        const float e0 = (l < i)    ? expf(v0 - mx) : 0.f;
        const float e1 = (l+64 < i) ? expf(v1 - mx) : 0.f;
        float sum = e0 + e1;
#pragma unroll
        for (int o = 32; o; o >>= 1) sum += __shfl_xor(sum, o);
        const float inv = 1.f / sum;
        if (l < i)    wgt[l]    = e0 * inv;
        if (l+64 < i) wgt[l+64] = e1 * inv;
      }
      __syncthreads();
      float acc = 0.f;
#pragma unroll 4
      for (int n = 0; n < i; ++n)
        acc = fmaf(wgt[n], H1[((long)n*64 + b)*SD2 + t], acc);
      Mlds[t] = acc;
      __syncthreads();
    }

    // gates: 6 rows (g*256+j) x M
    float a0 = 0.f, a1 = 0.f, a2 = 0.f, a3 = 0.f, a4 = 0.f, a5 = 0.f;
    {
      const float* wb = a.Wt + ((size_t)cd*64*1536 + j)*4;
#pragma unroll 2
      for (int kb = 0; kb < 64; ++kb) {
        const float4 m4 = *(const float4*)&Mlds[kb*4];
        const float* wr = wb + (size_t)kb*6144;
        const float4 w0 = *(const float4*)(wr);
        const float4 w1 = *(const float4*)(wr + 1024);
        const float4 w2 = *(const float4*)(wr + 2048);
        const float4 w3 = *(const float4*)(wr + 3072);
        const float4 w4 = *(const float4*)(wr + 4096);
        const float4 w5 = *(const float4*)(wr + 5120);
        a0 = fmaf(w0.x,m4.x,a0); a0 = fmaf(w0.y,m4.y,a0); a0 = fmaf(w0.z,m4.z,a0); a0 = fmaf(w0.w,m4.w,a0);
        a1 = fmaf(w1.x,m4.x,a1); a1 = fmaf(w1.y,m4.y,a1); a1 = fmaf(w1.z,m4.z,a1); a1 = fmaf(w1.w,m4.w,a1);
        a2 = fmaf(w2.x,m4.x,a2); a2 = fmaf(w2.y,m4.y,a2); a2 = fmaf(w2.z,m4.z,a2); a2 = fmaf(w2.w,m4.w,a2);
        a3 = fmaf(w3.x,m4.x,a3); a3 = fmaf(w3.y,m4.y,a3); a3 = fmaf(w3.z,m4.z,a3); a3 = fmaf(w3.w,m4.w,a3);
        a4 = fmaf(w4.x,m4.x,a4); a4 = fmaf(w4.y,m4.y,a4); a4 = fmaf(w4.z,m4.z,a4); a4 = fmaf(w4.w,m4.w,a4);
        a5 = fmaf(w5.x,m4.x,a5); a5 = fmaf(w5.y,m4.y,a5); a5 = fmaf(w5.z,m4.z,a5); a5 = fmaf(w5.w,m4.w,a5);
      }
    }
    // GRU elementwise + H1 row write
    {
      const int s = i - s0;
      const float gic_r = GKs[s*1536 + j];
      const float gic_z = GKs[s*1536 + 256 + j];
      const float gic_n = GKs[s*1536 + 512 + j];
      const float ghp_r = GKs[s*1536 + 768 + j];
      const float ghp_z = GKs[s*1536 + 1024 + j];
      const float ghp_n = GKs[s*1536 + 1280 + j];
      const float xj = Xp[((long)i*64 + b)*ldX + j];
      const float mj = Mlds[j];
      const float rC = sigm(gic_r + a0 + bc0);
      const float zC = sigm(gic_z + a1 + bc1);
      const float nC = tanhf(gic_n + rC * (a2 + bc2));
      const float Cc = (1.f - zC) * nC + zC * mj;
      const float rP = sigm(a3 + bp0 + ghp_r);
      const float zP = sigm(a4 + bp1 + ghp_z);
      const float nP = tanhf(a5 + bp2 + rP * ghp_n);
      H1[((long)i*64 + b)*SD2 + j] = Cc + (1.f - zP) * nP + zP * xj;
    }
    __threadfence_block();
    __syncthreads();
  }
}

__global__ void zero_k(float* p, long n)
{
  for (long idx = (long)blockIdx.x * 256 + threadIdx.x; idx < n; idx += (long)gridDim.x * 256)
    p[idx] = 0.f;
}

// column means of (8192 x 512), grid (8 colblocks, 32 rowslices), atomicAdd
__global__ void colmean_k(const float* __restrict__ X, float* __restrict__ mean)
{
  __shared__ float red[256];
  const int c = blockIdx.x * 64 + (threadIdx.x & 63), rq = threadIdx.x >> 6;
  const int r0 = blockIdx.y * 256;
  float acc = 0.f;
  for (int r = r0 + rq; r < r0 + 256; r += 4) acc += X[(long)r * SD2 + c];
  red[threadIdx.x] = acc;
  __syncthreads();
  if (threadIdx.x < 64) {
    const float s = red[threadIdx.x] + red[64 + threadIdx.x] + red[128 + threadIdx.x] + red[192 + threadIdx.x];
    atomicAdd(&mean[c], s * (1.f / 8192.f));
  }
}

__global__ void rownorm_k(const float* __restrict__ X, const float* __restrict__ mean,
                          float* __restrict__ inv)
{
  const int r = blockIdx.x * 4 + (threadIdx.x >> 6), lane = threadIdx.x & 63;
  const float* xp = X + (long)r * SD2 + lane * 8;
  const float4 v0 = *(const float4*)xp;
  const float4 v1 = *(const float4*)(xp + 4);
  const float4 m0 = *(const float4*)(mean + lane * 8);
  const float4 m1 = *(const float4*)(mean + lane * 8 + 4);
  float ss = 0.f, d;
  d = v0.x - m0.x; ss += d*d;  d = v0.y - m0.y; ss += d*d;
  d = v0.z - m0.z; ss += d*d;  d = v0.w - m0.w; ss += d*d;
  d = v1.x - m1.x; ss += d*d;  d = v1.y - m1.y; ss += d*d;
  d = v1.z - m1.z; ss += d*d;  d = v1.w - m1.w; ss += d*d;
  ss = wsum(ss);
  if (lane == 0) inv[r] = 1.f / (sqrtf(ss) + 1e-6f);
}

// partial G += xhat^T yhat over K slice; grid (8, 8, 16)
__global__ __launch_bounds__(256)
void gpart_k(const float* __restrict__ X, const float* __restrict__ Y,
             const float* __restrict__ mx, const float* __restrict__ my,
             const float* __restrict__ ix, const float* __restrict__ iy,
             float* __restrict__ G)
{
  __shared__ float As[16][68];
  __shared__ float Bs[16][68];
  __shared__ float mxs[64], mys[64];
  const int t = threadIdx.x, tx = t & 15, ty = t >> 4;
  const int ci = blockIdx.y * 64, cj = blockIdx.x * 64;
  if (t < 64) { mxs[t] = mx[ci + t]; mys[t] = my[cj + t]; }
  float acc[4][4];
#pragma unroll
  for (int ii = 0; ii < 4; ++ii)
#pragma unroll
    for (int jj = 0; jj < 4; ++jj) acc[ii][jj] = 0.f;
  const int rl = t >> 4, c4 = (t & 15) * 4;
  __syncthreads();
  const int kend = blockIdx.z * 512 + 512;
  for (int kb = blockIdx.z * 512; kb < kend; kb += 16) {
    const int r = kb + rl;
    const float4 xv = *(const float4*)(X + (long)r * SD2 + ci + c4);
    const float4 yv = *(const float4*)(Y + (long)r * SD2 + cj + c4);
    const float vx = ix[r], vy = iy[r];
    __syncthreads();
    As[rl][c4+0] = (xv.x - mxs[c4+0]) * vx; As[rl][c4+1] = (xv.y - mxs[c4+1]) * vx;
    As[rl][c4+2] = (xv.z - mxs[c4+2]) * vx; As[rl][c4+3] = (xv.w - mxs[c4+3]) * vx;
    Bs[rl][c4+0] = (yv.x - mys[c4+0]) * vy; Bs[rl][c4+1] = (yv.y - mys[c4+1]) * vy;
    Bs[rl][c4+2] = (yv.z - mys[c4+2]) * vy; Bs[rl][c4+3] = (yv.w - mys[c4+3]) * vy;
    __syncthreads();
#pragma unroll
    for (int kk = 0; kk < 16; ++kk) {
      float av[4], bv[4];
      *(float4*)&av[0] = *(const float4*)&As[kk][ty*4];
      *(float4*)&bv[0] = *(const float4*)&Bs[kk][tx*4];
#pragma unroll
      for (int ii = 0; ii < 4; ++ii)
#pragma unroll
        for (int jj = 0; jj < 4; ++jj)
          acc[ii][jj] = fmaf(av[ii], bv[jj], acc[ii][jj]);
    }
  }
#pragma unroll
  for (int ii = 0; ii < 4; ++ii)
#pragma unroll
    for (int jj = 0; jj < 4; ++jj)
      atomicAdd(&G[(long)(ci + ty*4 + ii) * SD2 + cj + tx*4 + jj], acc[ii][jj]);
}

__global__ void sqsum_k(const float* __restrict__ G, float* __restrict__ dl)
{
  __shared__ float red[4];
  float s = 0.f;
  const long base = (long)blockIdx.x * 1024;
#pragma unroll
  for (int it = 0; it < 4; ++it) { const float v = G[base + it*256 + threadIdx.x]; s += v*v; }
  s = wsum(s);
  const int lane = threadIdx.x & 63, wv = threadIdx.x >> 6;
  if (lane == 0) red[wv] = s;
  __syncthreads();
  if (threadIdx.x == 0) atomicAdd(dl, red[0] + red[1] + red[2] + red[3]);
}

// softmax over rows of length 128 (in-place)
__global__ void smax_k(float* __restrict__ S)
{
  const int r = blockIdx.x * 4 + (threadIdx.x >> 6), lane = threadIdx.x & 63;
  float* p = S + (long)r * SN;
  const float v0 = p[lane], v1 = p[lane + 64];
  float mx = fmaxf(v0, v1);
#pragma unroll
  for (int o = 32; o; o >>= 1) mx = fmaxf(mx, __shfl_xor(mx, o));
  const float e0 = expf(v0 - mx), e1 = expf(v1 - mx);
  float s = e0 + e1;
#pragma unroll
  for (int o = 32; o; o >>= 1) s += __shfl_xor(s, o);
  const float inv = 1.f / s;
  p[lane] = e0 * inv; p[lane + 64] = e1 * inv;
}

__global__ void head_k(const float* __restrict__ H, const float* __restrict__ W,
                       const float* __restrict__ bo, float* __restrict__ out)
{
  const int r = blockIdx.x * 4 + (threadIdx.x >> 6), lane = threadIdx.x & 63;
  const float4 h = *(const float4*)(H + (long)r * SD + lane * 4);
#pragma unroll
  for (int c = 0; c < SNC; ++c) {
    const float4 w = *(const float4*)(W + (long)c * SD + lane * 4);
    float p = h.x*w.x + h.y*w.y + h.z*w.z + h.w*w.w;
    p = wsum(p);
    if (lane == 0) out[(long)r * SNC + c] = p + bo[c];
  }
}

__global__ void fin_k(const float* __restrict__ dl, float* __restrict__ out)
{
  out[0] = (dl[0] + dl[1]) * (0.3f / (512.f * 512.f));
}

// ---------------------------------------------------------------------------
extern "C" void kernel_launch(void* const* d_in, const int* in_sizes, int n_in,
                              void* d_out, int out_size, void* d_ws, size_t ws_size,
                              hipStream_t stream)
{
  (void)in_sizes; (void)n_in; (void)out_size; (void)ws_size;
  const float* F    = (const float*)d_in[0];
  const int*   adj1 = (const int*)  d_in[1];
  const int*   adj2 = (const int*)  d_in[2];
  const float* fc1w = (const float*)d_in[6];
  const float* fc1b = (const float*)d_in[7];
  const float *g_wih[4], *g_whh[4], *g_bih[4], *g_bhh[4];  // gcs, gps, gcl, gpl
  for (int g = 0; g < 4; ++g) {
    g_wih[g] = (const float*)d_in[8 + g*4 + 0];
    g_whh[g] = (const float*)d_in[8 + g*4 + 1];
    g_bih[g] = (const float*)d_in[8 + g*4 + 2];
    g_bhh[g] = (const float*)d_in[8 + g*4 + 3];
  }
  const float* gat_wq[2] = {(const float*)d_in[24], (const float*)d_in[28]};
  const float* gat_bq[2] = {(const float*)d_in[25], (const float*)d_in[29]};
  const float* gat_wk[2] = {(const float*)d_in[26], (const float*)d_in[30]};
  const float* gat_bk[2] = {(const float*)d_in[27], (const float*)d_in[31]};
  const float* aff1 = (const float*)d_in[32];
  const float* aff2 = (const float*)d_in[33];
  const float* mw1  = (const float*)d_in[34];
  const float* mb1  = (const float*)d_in[35];
  const float* mw2  = (const float*)d_in[36];
  const float* mb2  = (const float*)d_in[37];
  const float* ow   = (const float*)d_in[38];
  const float* ob   = (const float*)d_in[39];
  float* out = (float*)d_out;

  // ---- workspace layout ----
  float* ws = (float*)d_ws;
  size_t off = 0;
  auto take = [&](size_t nf){ float* p = ws + off; off += nf; return p; };
  float* region = take(22552576);           // overlay region
  float* X0f  = region;                     // 2,097,152 (time-major layer-0 fwd)
  float* X0r  = region + 2097152;           // 2,097,152 (time-major layer-0 bwd)
  float* Qtb  = region + 4194304;           // 4 x 2,097,152
  float* Qtmp = region + 12582912;          // 2,097,152
  float* Htmp = region + 14680064;          // b-major H0 temp (early only)
  // finals overlay (sequential-phase buffers dead by then)
  float* T  = region;                       // 4,194,304
  float* Sb = region + 4194304;             // 1,048,576
  float* HH = region + 5242880;             // 4,194,304
  float* h1 = region + 9437184;             // 2,097,152
  float* h2 = region + 11534336;            // 2,097,152
  float* Ocat[2][2];                        // time-major H1 storage, stride 512
  for (int c = 0; c < 2; ++c) for (int l = 0; l < 2; ++l) Ocat[c][l] = take(4194304);
  float* S0b   = take(32768);               // 4 x 8192
  float* WtB   = take(1572864);             // [cd][64][1536][4] step weights
  float* WgkB  = take(1572864);             // [cd][64][1536][4] GK weights
  float* meanx = take(512);
  float* meany = take(512);
  float* invx  = take(8192);
  float* invy  = take(8192);
  float* dl    = take(8);
  float* Gbuf  = take(262144);

  // H0 = relu(F @ fc1w^T + fc1b)  (b-major temp), then spread to time-major
  gemm_k<false,true,true,false><<<dim3(4,64,1),256,0,stream>>>(
      F, fc1w, fc1b, Htmp, SD, SE, SE, SE, SD, 0,0,0);
  spread_k<<<SBN,256,0,stream>>>(Htmp, X0f, X0r);

  for (int l = 0; l < 2; ++l) {
    PTArgs pt, pg; StepArgs sta;
    sta.ldX = l ? SD2 : SD;
    sta.Wt = WtB; sta.Wgk = WgkB;
    const int ldX = sta.ldX;
    for (int cd = 0; cd < 4; ++cd) {
      const int ch = cd >> 1;  // 0 = s-channel, 1 = l-channel
      const float* X = (l == 0) ? ((cd & 1) ? X0r : X0f)
                                : (Ocat[ch][0] + (cd & 1) * SD);
      const float* wq   = gat_wq[ch] + l * SD * SD;
      const float* bq   = gat_bq[ch] + l * SD;
      const float* wk   = gat_wk[ch] + l * SD * SD;
      const float* bk   = gat_bk[ch] + l * SD;
      const float* cwih = g_wih[ch*2+0] + l * SD3 * SD;
      const float* cwhh = g_whh[ch*2+0] + l * SD3 * SD;
      const float* cbih = g_bih[ch*2+0] + l * SD3;
      const float* cbhh = g_bhh[ch*2+0] + l * SD3;
      const float* pwih = g_wih[ch*2+1] + l * SD3 * SD;
      const float* pwhh = g_whh[ch*2+1] + l * SD3 * SD;
      const float* pbih = g_bih[ch*2+1] + l * SD3;
      const float* pbhh = g_bhh[ch*2+1] + l * SD3;
      pt.wc[cd] = cwhh; pt.wp[cd] = pwih;   // step-gate weights
      pg.wc[cd] = cwih; pg.wp[cd] = pwhh;   // GK weights
      // Qtmp = X@wq^T + bq ; Qt = Qtmp@wk ; S0 = Qtmp . bk
      gemm_k<false,true,false,false><<<dim3(4,64,1),256,0,stream>>>(
          X, wq, bq, Qtmp, SD, SD, ldX, SD, SD, 0,0,0);
      gemm_k<true,false,false,false><<<dim3(4,64,1),256,0,stream>>>(
          Qtmp, wk, nullptr, Qtb + (size_t)cd*2097152, SD, SD, SD, SD, SD, 0,0,0);
      s0_k<<<SBN/4,256,0,stream>>>(Qtmp, bk, S0b + cd*SBN);
      float* H1mut = Ocat[ch][l] + (cd & 1) * SD;
      sta.Qt[cd] = Qtb + (size_t)cd*2097152;
      sta.S0[cd] = S0b + cd*SBN;
      sta.H1[cd] = H1mut;
      sta.adj[cd] = ch ? adj2 : adj1; sta.rev[cd] = cd & 1;
      sta.bc[cd]  = cbhh; sta.bp[cd]  = pbih;
      sta.bgc[cd] = cbih; sta.bgp[cd] = pbhh;
      sta.X[cd] = X;
    }
    pt.Wt = WtB;  packT_k<<<dim3(64,4),256,0,stream>>>(pt);
    pg.Wt = WgkB; packT_k<<<dim3(64,4),256,0,stream>>>(pg);

    for (int s0 = 0; s0 < SN; s0 += CS) {
      sta.s0 = s0;
      step_chunk_k<<<256,256,0,stream>>>(sta);
    }
  }

  // diff loss (row-permutation invariant -> time-major OK)
  zero_k<<<1,256,0,stream>>>(dl, 2);
  for (int l = 0; l < 2; ++l) {
    zero_k<<<4,256,0,stream>>>(meanx, 1024);  // meanx+meany contiguous
    colmean_k<<<dim3(8,32,1),256,0,stream>>>(Ocat[0][l], meanx);
    colmean_k<<<dim3(8,32,1),256,0,stream>>>(Ocat[1][l], meany);
    rownorm_k<<<SBN/4,256,0,stream>>>(Ocat[0][l], meanx, invx);
    rownorm_k<<<SBN/4,256,0,stream>>>(Ocat[1][l], meany, invy);
    zero_k<<<256,256,0,stream>>>(Gbuf, (long)SD2*SD2);
    gpart_k<<<dim3(8,8,16),256,0,stream>>>(Ocat[0][l], Ocat[1][l], meanx, meany, invx, invy, Gbuf);
    sqsum_k<<<256,256,0,stream>>>(Gbuf, dl + l);
  }

  // cross attention + final MLP (h1 accumulated from F / HSn / HLn slices)
  gemm_k<true,false,false,false><<<dim3(8,64,1),256,0,stream>>>(
      Ocat[0][1], aff1, nullptr, T, SD2, SD2, SD2, SD2, SD2, 0,0,0);
  gemm_k<false,false,false,false><<<dim3(2,1,64),256,0,stream>>>(
      T, Ocat[1][1], nullptr, Sb, SN, SD2, 64*SD2, 64*SD2, SN, SD2, SD2, (long)SN*SN);
  smax_k<<<SBN/4,256,0,stream>>>(Sb);
  gemm_k<true,false,false,false><<<dim3(8,1,64),256,0,stream>>>(
      Sb, Ocat[1][1], nullptr, HH, SD2, SN, SN, 64*SD2, SD2, (long)SN*SN, SD2, (long)SN*SD2);
  gemm_k<false,true,false,false><<<dim3(4,64,1),256,0,stream>>>(
      F, mw1, mb1, h1, SD, SE, SE, SIN, SD, 0,0,0);
  gemm_k<false,false,false,true><<<dim3(4,64,1),256,0,stream>>>(
      HH, mw1 + 1024, nullptr, h1, SD, SD2, SD2, SIN, SD, 0,0,0);
  gemm_k<true,false,false,false><<<dim3(8,64,1),256,0,stream>>>(
      Ocat[1][1], aff2, nullptr, T, SD2, SD2, SD2, SD2, SD2, 0,0,0);
  gemm_k<false,false,false,false><<<dim3(2,1,64),256,0,stream>>>(
      T, Ocat[0][1], nullptr, Sb, SN, SD2, 64*SD2, 64*SD2, SN, SD2, SD2, (long)SN*SN);
  smax_k<<<SBN/4,256,0,stream>>>(Sb);
  gemm_k<true,false,false,false><<<dim3(8,1,64),256,0,stream>>>(
      Sb, Ocat[0][1], nullptr, HH, SD2, SN, SN, 64*SD2, SD2, (long)SN*SN, SD2, (long)SN*SD2);
  gemm_k<false,false,true,true><<<dim3(4,64,1),256,0,stream>>>(
      HH, mw1 + 1536, nullptr, h1, SD, SD2, SD2, SIN, SD, 0,0,0);
  gemm_k<false,true,true,false><<<dim3(4,64,1),256,0,stream>>>(
      h1, mw2, mb2, h2, SD, SD, SD, SD, SD, 0,0,0);
  head_k<<<SBN/4,256,0,stream>>>(h2, ow, ob, out);
  fin_k<<<1,1,0,stream>>>(dl, out + SBN * SNC);
}

// Round 9
// 7175.762 us; speedup vs baseline: 6.2585x; 1.3117x over previous
//
#include <hip/hip_runtime.h>
#include <hip/hip_fp16.h>
#include <math.h>

// Problem constants
#define SB   64     // batch
#define SN   128    // seq len
#define SE   1024   // feature dim
#define SD   256    // hidden D
#define SD2  512    // 2D
#define SD3  768    // 3D
#define SIN  2048   // 4D+E
#define SNC  7
#define SBN  8192   // SB*SN
#define CS   8      // chunk steps (GK tile held in LDS)

__device__ __forceinline__ float wsum(float v){
#pragma unroll
  for (int o = 32; o; o >>= 1) v += __shfl_xor(v, o);
  return v;
}
__device__ __forceinline__ float sigm(float x){ return 1.f/(1.f + expf(-x)); }

__device__ __forceinline__ unsigned short f2h(float f){
  return __half_as_ushort(__float2half_rn(f));
}
// dot of 8 fp16 weights (packed in uint4) with 8 fp32 M values
__device__ __forceinline__ float dot8h(uint4 w, float4 ma, float4 mb, float acc){
  const float2 p0 = __half22float2(*(__half2*)&w.x);
  const float2 p1 = __half22float2(*(__half2*)&w.y);
  const float2 p2 = __half22float2(*(__half2*)&w.z);
  const float2 p3 = __half22float2(*(__half2*)&w.w);
  acc = fmaf(p0.x, ma.x, acc);
  acc = fmaf(p0.y, ma.y, acc);
  acc = fmaf(p1.x, ma.z, acc);
  acc = fmaf(p1.y, ma.w, acc);
  acc = fmaf(p2.x, mb.x, acc);
  acc = fmaf(p2.y, mb.y, acc);
  acc = fmaf(p3.x, mb.z, acc);
  acc = fmaf(p3.y, mb.w, acc);
  return acc;
}

// ---------------------------------------------------------------------------
// Generic fp32 GEMM: C[M,N] = A @ op(B) (+bias)(+acc)(+relu), batched via z.
// BKMAJ=false: B rows are N (NT).  BKMAJ=true: B rows are K (NN).
// BM=128, BN=64, BK=16, 256 threads, 8x4 micro-tile.
// ---------------------------------------------------------------------------
template<bool BKMAJ, bool BIAS, bool RELU, bool ACC>
__global__ __launch_bounds__(256)
void gemm_k(const float* __restrict__ A, const float* __restrict__ Bm,
            const float* __restrict__ bias, float* __restrict__ C,
            int Nn, int K, int lda, int ldb, int ldc,
            long sA, long sB, long sC)
{
  __shared__ float As[16][132];
  __shared__ float Bs[16][68];
  const int t  = threadIdx.x;
  const int tx = t & 15, ty = t >> 4;
  const float* Ab = A + (long)blockIdx.z * sA;
  const float* Bb = Bm + (long)blockIdx.z * sB;
  float* Cb = C + (long)blockIdx.z * sC;
  const int m0 = blockIdx.y * 128, n0 = blockIdx.x * 64;
  float acc[8][4];
#pragma unroll
  for (int i = 0; i < 8; ++i)
#pragma unroll
    for (int j = 0; j < 4; ++j) acc[i][j] = 0.f;

  const int am = t >> 1, ak = (t & 1) * 8;
  int bn_ = 0, bk_ = 0;
  if (BKMAJ) { bk_ = t >> 4; bn_ = (t & 15) * 4; }
  else       { bn_ = t >> 2; bk_ = (t & 3) * 4; }

  for (int k0 = 0; k0 < K; k0 += 16) {
    const float4 a0 = *(const float4*)(Ab + (long)(m0 + am) * lda + k0 + ak);
    const float4 a1 = *(const float4*)(Ab + (long)(m0 + am) * lda + k0 + ak + 4);
    float4 b0;
    if (BKMAJ) b0 = *(const float4*)(Bb + (long)(k0 + bk_) * ldb + n0 + bn_);
    else       b0 = *(const float4*)(Bb + (long)(n0 + bn_) * ldb + k0 + bk_);
    __syncthreads();
    As[ak+0][am] = a0.x; As[ak+1][am] = a0.y; As[ak+2][am] = a0.z; As[ak+3][am] = a0.w;
    As[ak+4][am] = a1.x; As[ak+5][am] = a1.y; As[ak+6][am] = a1.z; As[ak+7][am] = a1.w;
    if (BKMAJ) { *(float4*)&Bs[bk_][bn_] = b0; }
    else { Bs[bk_+0][bn_] = b0.x; Bs[bk_+1][bn_] = b0.y; Bs[bk_+2][bn_] = b0.z; Bs[bk_+3][bn_] = b0.w; }
    __syncthreads();
#pragma unroll
    for (int kk = 0; kk < 16; ++kk) {
      float av[8], bv[4];
      *(float4*)&av[0] = *(const float4*)&As[kk][ty*8];
      *(float4*)&av[4] = *(const float4*)&As[kk][ty*8+4];
      *(float4*)&bv[0] = *(const float4*)&Bs[kk][tx*4];
#pragma unroll
      for (int ii = 0; ii < 8; ++ii)
#pragma unroll
        for (int jj = 0; jj < 4; ++jj)
          acc[ii][jj] = fmaf(av[ii], bv[jj], acc[ii][jj]);
    }
  }
#pragma unroll
  for (int ii = 0; ii < 8; ++ii) {
#pragma unroll
    for (int jj = 0; jj < 4; ++jj) {
      float v = acc[ii][jj];
      if (BIAS) v += bias[n0 + tx*4 + jj];
      const long ci = (long)(m0 + ty*8 + ii) * ldc + n0 + tx*4 + jj;
      if (ACC) v += Cb[ci];
      if (RELU) v = fmaxf(v, 0.f);
      Cb[ci] = v;
    }
  }
}

// Htmp is b-major (row b*128+n). Write time-major X0f[(n*64+b)] and reversed.
__global__ void spread_k(const float* __restrict__ src, float* __restrict__ xf,
                         float* __restrict__ xr)
{
  const int r = blockIdx.x, t = threadIdx.x;   // src row = b*128+n
  const int b = r >> 7, n = r & 127;
  const float v = src[(long)r * SD + t];
  xf[((long)(n * 64 + b)) * SD + t] = v;
  xr[((long)((127 - n) * 64 + b)) * SD + t] = v;
}

// Pack transposed fp16 weights: Wt[cd][kb8][row][8] = fp16(W[row][kb8*8+q]),
// rows 0..767 from wc, 768..1535 from wp.  Grid (32 kb8, 4 cd).
struct PTArgs { const float* wc[4]; const float* wp[4]; unsigned short* Wt; };
__global__ void packT_k(PTArgs a)
{
  const int kb8 = blockIdx.x, cd = blockIdx.y, t = threadIdx.x;
#pragma unroll
  for (int p = 0; p < 6; ++p) {
    const int r = t + 256 * p;
    const float* src = (r < 768) ? (a.wc[cd] + (long)r * SD)
                                 : (a.wp[cd] + (long)(r - 768) * SD);
    const float4 v0 = *(const float4*)(src + kb8 * 8);
    const float4 v1 = *(const float4*)(src + kb8 * 8 + 4);
    uint4 o;
    o.x = (unsigned)f2h(v0.x) | ((unsigned)f2h(v0.y) << 16);
    o.y = (unsigned)f2h(v0.z) | ((unsigned)f2h(v0.w) << 16);
    o.z = (unsigned)f2h(v1.x) | ((unsigned)f2h(v1.y) << 16);
    o.w = (unsigned)f2h(v1.z) | ((unsigned)f2h(v1.w) << 16);
    *(uint4*)(a.Wt + (((size_t)cd * 32 + kb8) * 1536 + r) * 8) = o;
  }
}

// S0[m] = Q[m,:] . bk
__global__ void s0_k(const float* __restrict__ Q, const float* __restrict__ bk,
                     float* __restrict__ S0)
{
  const int r = blockIdx.x * 4 + (threadIdx.x >> 6), lane = threadIdx.x & 63;
  const float4 q  = *(const float4*)(Q + (long)r * SD + lane * 4);
  const float4 kb = *(const float4*)(bk + lane * 4);
  float p = q.x*kb.x + q.y*kb.y + q.z*kb.z + q.w*kb.w;
  p = wsum(p);
  if (lane == 0) S0[r] = p;
}

// ---------------------------------------------------------------------------
// Chunk step kernel: CS sequential DAG steps in one launch.
// 256 blocks = one BLOCK per (cd, b) chain; cd = blk & 3 pins each cd's
// weight stream to 2 XCDs' L2 (fp16-packed: 0.75 MB/cd). Per chunk: GK phase
// (gate-input precompute for CS steps into LDS), then CS x (attention -> M in
// LDS -> 1536-row gate dot (6 rows/thread) -> GRU -> H1 row write).
// Row indexing in the packed stream: 1 row = 8 shorts = 1 uint4, so gate g's
// row (g*256+j) sits at uint4 offset g*256 from row j.  (Round-7/8 bug: used
// g*128 — wrong rows, precision-independent failure.)
// ---------------------------------------------------------------------------
struct StepArgs {
  const float* Qt[4]; const float* S0[4];
  const int* adj[4]; int rev[4];
  const float* bc[4];  const float* bp[4];   // cbhh, pbih (step-gate biases)
  const float* bgc[4]; const float* bgp[4];  // cbih, pbhh (GK biases)
  const float* X[4];
  float* H1[4];                              // time-major stride SD2, col-offset baked
  const unsigned short* Wt;   // fp16 [cd][32][1536][8]: rows 0..767 cwhh, 768..1535 pwih
  const unsigned short* Wgk;  // fp16 [cd][32][1536][8]: rows 0..767 cwih, 768..1535 pwhh
  int ldX, s0;
};
__global__ __launch_bounds__(256, 1) void step_chunk_k(StepArgs a)
{
  __shared__ float smem[14976];   // 59.9 KB
  float* GKs  = smem;             // [CS][1536]
  float* Xs   = smem + 12288;     // [CS][256]
  float* Mlds = smem + 14336;     // [256]
  float* lg   = smem + 14592;     // [128]
  float* wgt  = smem + 14720;     // [128]
  float* adjm = smem + 14848;     // [128]

  const int blk = blockIdx.x;
  const int cd = blk & 3, b = blk >> 2;
  const int t = threadIdx.x, q = t >> 6, l = t & 63;
  const int j = t;                        // output column 0..255
  const int ldX = a.ldX, s0 = a.s0;
  const float* Xp  = a.X[cd];
  float* H1 = a.H1[cd];
  const float* Qtp = a.Qt[cd];
  const float* S0p = a.S0[cd];
  const int*   adjp = a.adj[cd];
  const int    rev  = a.rev[cd];

  // hoisted biases for this thread's column j
  const float bc0 = a.bc[cd][j],  bc1 = a.bc[cd][256+j],  bc2 = a.bc[cd][512+j];
  const float bp0 = a.bp[cd][j],  bp1 = a.bp[cd][256+j],  bp2 = a.bp[cd][512+j];

  // ---- GK phase: GKs[s][g*256+j] = X[s0+s,b] . Wgk_row(g*256+j) + bias ----
#pragma unroll
  for (int s = 0; s < CS; ++s)
    Xs[s*256 + t] = Xp[((long)(s0+s)*64 + b)*ldX + t];
  __syncthreads();
  {
    float gacc[6][CS];
#pragma unroll
    for (int g = 0; g < 6; ++g)
#pragma unroll
      for (int s = 0; s < CS; ++s) gacc[g][s] = 0.f;
    const unsigned short* wbase = a.Wgk + ((size_t)cd*32*1536 + j)*8;
    for (int kb8 = 0; kb8 < 32; ++kb8) {
      const uint4* wr = (const uint4*)(wbase + (size_t)kb8*12288);
      uint4 w[6];
#pragma unroll
      for (int g = 0; g < 6; ++g) w[g] = wr[g*256];   // 1 row = 1 uint4; gate stride 256 rows
#pragma unroll
      for (int s = 0; s < CS; ++s) {
        const float4 xa = *(const float4*)&Xs[s*256 + kb8*8];
        const float4 xb = *(const float4*)&Xs[s*256 + kb8*8 + 4];
#pragma unroll
        for (int g = 0; g < 6; ++g)
          gacc[g][s] = dot8h(w[g], xa, xb, gacc[g][s]);
      }
    }
#pragma unroll
    for (int g = 0; g < 6; ++g) {
      const float bg = (g < 3) ? a.bgc[cd][g*256 + j] : a.bgp[cd][(g-3)*256 + j];
#pragma unroll
      for (int s = 0; s < CS; ++s)
        GKs[s*1536 + g*256 + j] = gacc[g][s] + bg;
    }
  }
  __syncthreads();

  // ---- CS sequential steps ----
  for (int i = s0; i < s0 + CS; ++i) {
    if (i == 0) {
      Mlds[t] = 0.f;
      __syncthreads();
    } else {
      if (t < 128) {
        const int ii = rev ? (SN-1-i) : i;
        const int nn = rev ? (SN-1-t) : t;
        adjm[t] = (float)adjp[((long)b*SN + ii)*SN + nn];
      }
      const float4 q4 = *(const float4*)(Qtp + ((long)i*64 + b)*SD + l*4);
      for (int n = q; n < i; n += 4) {
        const float4 h4 = *(const float4*)(H1 + ((long)n*64 + b)*SD2 + l*4);
        float p = q4.x*h4.x + q4.y*h4.y + q4.z*h4.z + q4.w*h4.w;
        p = wsum(p);
        if (l == 0) lg[n] = p;
      }
      __syncthreads();
      if (q == 0) {
        const float s0v = S0p[i*64 + b];
        const float v0 = (l < i)    ? (lg[l]    + s0v - (1.f - adjm[l]   )*1e30f) : -3.0e38f;
        const float v1 = (l+64 < i) ? (lg[l+64] + s0v - (1.f - adjm[l+64])*1e30f) : -3.0e38f;
        float mx = fmaxf(v0, v1);
#pragma unroll
        for (int o = 32; o; o >>= 1) mx = fmaxf(mx, __shfl_xor(mx, o));
        const float e0 = (l < i)    ? expf(v0 - mx) : 0.f;
        const float e1 = (l+64 < i) ? expf(v1 - mx) : 0.f;
        float sum = e0 + e1;
#pragma unroll
        for (int o = 32; o; o >>= 1) sum += __shfl_xor(sum, o);
        const float inv = 1.f / sum;
        if (l < i)    wgt[l]    = e0 * inv;
        if (l+64 < i) wgt[l+64] = e1 * inv;
      }
      __syncthreads();
      float acc = 0.f;
#pragma unroll 4
      for (int n = 0; n < i; ++n)
        acc = fmaf(wgt[n], H1[((long)n*64 + b)*SD2 + t], acc);
      Mlds[t] = acc;
      __syncthreads();
    }

    // gates: 6 rows (g*256+j) x M, fp16 weights (row = 1 uint4 -> offsets g*256)
    float a0 = 0.f, a1 = 0.f, a2 = 0.f, a3 = 0.f, a4 = 0.f, a5 = 0.f;
    {
      const unsigned short* wb = a.Wt + ((size_t)cd*32*1536 + j)*8;
#pragma unroll 2
      for (int kb8 = 0; kb8 < 32; ++kb8) {
        const float4 ma = *(const float4*)&Mlds[kb8*8];
        const float4 mb = *(const float4*)&Mlds[kb8*8 + 4];
        const uint4* wr = (const uint4*)(wb + (size_t)kb8*12288);
        const uint4 w0 = wr[0];
        const uint4 w1 = wr[256];
        const uint4 w2 = wr[512];
        const uint4 w3 = wr[768];
        const uint4 w4 = wr[1024];
        const uint4 w5 = wr[1280];
        a0 = dot8h(w0, ma, mb, a0);
        a1 = dot8h(w1, ma, mb, a1);
        a2 = dot8h(w2, ma, mb, a2);
        a3 = dot8h(w3, ma, mb, a3);
        a4 = dot8h(w4, ma, mb, a4);
        a5 = dot8h(w5, ma, mb, a5);
      }
    }
    // GRU elementwise + H1 row write
    {
      const int s = i - s0;
      const float gic_r = GKs[s*1536 + j];
      const float gic_z = GKs[s*1536 + 256 + j];
      const float gic_n = GKs[s*1536 + 512 + j];
      const float ghp_r = GKs[s*1536 + 768 + j];
      const float ghp_z = GKs[s*1536 + 1024 + j];
      const float ghp_n = GKs[s*1536 + 1280 + j];
      const float xj = Xp[((long)i*64 + b)*ldX + j];
      const float mj = Mlds[j];
      const float rC = sigm(gic_r + a0 + bc0);
      const float zC = sigm(gic_z + a1 + bc1);
      const float nC = tanhf(gic_n + rC * (a2 + bc2));
      const float Cc = (1.f - zC) * nC + zC * mj;
      const float rP = sigm(a3 + bp0 + ghp_r);
      const float zP = sigm(a4 + bp1 + ghp_z);
      const float nP = tanhf(a5 + bp2 + rP * ghp_n);
      H1[((long)i*64 + b)*SD2 + j] = Cc + (1.f - zP) * nP + zP * xj;
    }
    __threadfence_block();
    __syncthreads();
  }
}

__global__ void zero_k(float* p, long n)
{
  for (long idx = (long)blockIdx.x * 256 + threadIdx.x; idx < n; idx += (long)gridDim.x * 256)
    p[idx] = 0.f;
}

// column means of (8192 x 512), grid (8 colblocks, 32 rowslices), atomicAdd
__global__ void colmean_k(const float* __restrict__ X, float* __restrict__ mean)
{
  __shared__ float red[256];
  const int c = blockIdx.x * 64 + (threadIdx.x & 63), rq = threadIdx.x >> 6;
  const int r0 = blockIdx.y * 256;
  float acc = 0.f;
  for (int r = r0 + rq; r < r0 + 256; r += 4) acc += X[(long)r * SD2 + c];
  red[threadIdx.x] = acc;
  __syncthreads();
  if (threadIdx.x < 64) {
    const float s = red[threadIdx.x] + red[64 + threadIdx.x] + red[128 + threadIdx.x] + red[192 + threadIdx.x];
    atomicAdd(&mean[c], s * (1.f / 8192.f));
  }
}

__global__ void rownorm_k(const float* __restrict__ X, const float* __restrict__ mean,
                          float* __restrict__ inv)
{
  const int r = blockIdx.x * 4 + (threadIdx.x >> 6), lane = threadIdx.x & 63;
  const float* xp = X + (long)r * SD2 + lane * 8;
  const float4 v0 = *(const float4*)xp;
  const float4 v1 = *(const float4*)(xp + 4);
  const float4 m0 = *(const float4*)(mean + lane * 8);
  const float4 m1 = *(const float4*)(mean + lane * 8 + 4);
  float ss = 0.f, d;
  d = v0.x - m0.x; ss += d*d;  d = v0.y - m0.y; ss += d*d;
  d = v0.z - m0.z; ss += d*d;  d = v0.w - m0.w; ss += d*d;
  d = v1.x - m1.x; ss += d*d;  d = v1.y - m1.y; ss += d*d;
  d = v1.z - m1.z; ss += d*d;  d = v1.w - m1.w; ss += d*d;
  ss = wsum(ss);
  if (lane == 0) inv[r] = 1.f / (sqrtf(ss) + 1e-6f);
}

// partial G += xhat^T yhat over K slice; grid (8, 8, 16)
__global__ __launch_bounds__(256)
void gpart_k(const float* __restrict__ X, const float* __restrict__ Y,
             const float* __restrict__ mx, const float* __restrict__ my,
             const float* __restrict__ ix, const float* __restrict__ iy,
             float* __restrict__ G)
{
  __shared__ float As[16][68];
  __shared__ float Bs[16][68];
  __shared__ float mxs[64], mys[64];
  const int t = threadIdx.x, tx = t & 15, ty = t >> 4;
  const int ci = blockIdx.y * 64, cj = blockIdx.x * 64;
  if (t < 64) { mxs[t] = mx[ci + t]; mys[t] = my[cj + t]; }
  float acc[4][4];
#pragma unroll
  for (int ii = 0; ii < 4; ++ii)
#pragma unroll
    for (int jj = 0; jj < 4; ++jj) acc[ii][jj] = 0.f;
  const int rl = t >> 4, c4 = (t & 15) * 4;
  __syncthreads();
  const int kend = blockIdx.z * 512 + 512;
  for (int kb = blockIdx.z * 512; kb < kend; kb += 16) {
    const int r = kb + rl;
    const float4 xv = *(const float4*)(X + (long)r * SD2 + ci + c4);
    const float4 yv = *(const float4*)(Y + (long)r * SD2 + cj + c4);
    const float vx = ix[r], vy = iy[r];
    __syncthreads();
    As[rl][c4+0] = (xv.x - mxs[c4+0]) * vx; As[rl][c4+1] = (xv.y - mxs[c4+1]) * vx;
    As[rl][c4+2] = (xv.z - mxs[c4+2]) * vx; As[rl][c4+3] = (xv.w - mxs[c4+3]) * vx;
    Bs[rl][c4+0] = (yv.x - mys[c4+0]) * vy; Bs[rl][c4+1] = (yv.y - mys[c4+1]) * vy;
    Bs[rl][c4+2] = (yv.z - mys[c4+2]) * vy; Bs[rl][c4+3] = (yv.w - mys[c4+3]) * vy;
    __syncthreads();
#pragma unroll
    for (int kk = 0; kk < 16; ++kk) {
      float av[4], bv[4];
      *(float4*)&av[0] = *(const float4*)&As[kk][ty*4];
      *(float4*)&bv[0] = *(const float4*)&Bs[kk][tx*4];
#pragma unroll
      for (int ii = 0; ii < 4; ++ii)
#pragma unroll
        for (int jj = 0; jj < 4; ++jj)
          acc[ii][jj] = fmaf(av[ii], bv[jj], acc[ii][jj]);
    }
  }
#pragma unroll
  for (int ii = 0; ii < 4; ++ii)
#pragma unroll
    for (int jj = 0; jj < 4; ++jj)
      atomicAdd(&G[(long)(ci + ty*4 + ii) * SD2 + cj + tx*4 + jj], acc[ii][jj]);
}

__global__ void sqsum_k(const float* __restrict__ G, float* __restrict__ dl)
{
  __shared__ float red[4];
  float s = 0.f;
  const long base = (long)blockIdx.x * 1024;
#pragma unroll
  for (int it = 0; it < 4; ++it) { const float v = G[base + it*256 + threadIdx.x]; s += v*v; }
  s = wsum(s);
  const int lane = threadIdx.x & 63, wv = threadIdx.x >> 6;
  if (lane == 0) red[wv] = s;
  __syncthreads();
  if (threadIdx.x == 0) atomicAdd(dl, red[0] + red[1] + red[2] + red[3]);
}

// softmax over rows of length 128 (in-place)
__global__ void smax_k(float* __restrict__ S)
{
  const int r = blockIdx.x * 4 + (threadIdx.x >> 6), lane = threadIdx.x & 63;
  float* p = S + (long)r * SN;
  const float v0 = p[lane], v1 = p[lane + 64];
  float mx = fmaxf(v0, v1);
#pragma unroll
  for (int o = 32; o; o >>= 1) mx = fmaxf(mx, __shfl_xor(mx, o));
  const float e0 = expf(v0 - mx), e1 = expf(v1 - mx);
  float s = e0 + e1;
#pragma unroll
  for (int o = 32; o; o >>= 1) s += __shfl_xor(s, o);
  const float inv = 1.f / s;
  p[lane] = e0 * inv; p[lane + 64] = e1 * inv;
}

__global__ void head_k(const float* __restrict__ H, const float* __restrict__ W,
                       const float* __restrict__ bo, float* __restrict__ out)
{
  const int r = blockIdx.x * 4 + (threadIdx.x >> 6), lane = threadIdx.x & 63;
  const float4 h = *(const float4*)(H + (long)r * SD + lane * 4);
#pragma unroll
  for (int c = 0; c < SNC; ++c) {
    const float4 w = *(const float4*)(W + (long)c * SD + lane * 4);
    float p = h.x*w.x + h.y*w.y + h.z*w.z + h.w*w.w;
    p = wsum(p);
    if (lane == 0) out[(long)r * SNC + c] = p + bo[c];
  }
}

__global__ void fin_k(const float* __restrict__ dl, float* __restrict__ out)
{
  out[0] = (dl[0] + dl[1]) * (0.3f / (512.f * 512.f));
}

// ---------------------------------------------------------------------------
extern "C" void kernel_launch(void* const* d_in, const int* in_sizes, int n_in,
                              void* d_out, int out_size, void* d_ws, size_t ws_size,
                              hipStream_t stream)
{
  (void)in_sizes; (void)n_in; (void)out_size; (void)ws_size;
  const float* F    = (const float*)d_in[0];
  const int*   adj1 = (const int*)  d_in[1];
  const int*   adj2 = (const int*)  d_in[2];
  const float* fc1w = (const float*)d_in[6];
  const float* fc1b = (const float*)d_in[7];
  const float *g_wih[4], *g_whh[4], *g_bih[4], *g_bhh[4];  // gcs, gps, gcl, gpl
  for (int g = 0; g < 4; ++g) {
    g_wih[g] = (const float*)d_in[8 + g*4 + 0];
    g_whh[g] = (const float*)d_in[8 + g*4 + 1];
    g_bih[g] = (const float*)d_in[8 + g*4 + 2];
    g_bhh[g] = (const float*)d_in[8 + g*4 + 3];
  }
  const float* gat_wq[2] = {(const float*)d_in[24], (const float*)d_in[28]};
  const float* gat_bq[2] = {(const float*)d_in[25], (const float*)d_in[29]};
  const float* gat_wk[2] = {(const float*)d_in[26], (const float*)d_in[30]};
  const float* gat_bk[2] = {(const float*)d_in[27], (const float*)d_in[31]};
  const float* aff1 = (const float*)d_in[32];
  const float* aff2 = (const float*)d_in[33];
  const float* mw1  = (const float*)d_in[34];
  const float* mb1  = (const float*)d_in[35];
  const float* mw2  = (const float*)d_in[36];
  const float* mb2  = (const float*)d_in[37];
  const float* ow   = (const float*)d_in[38];
  const float* ob   = (const float*)d_in[39];
  float* out = (float*)d_out;

  // ---- workspace layout ----
  float* ws = (float*)d_ws;
  size_t off = 0;
  auto take = [&](size_t nf){ float* p = ws + off; off += nf; return p; };
  float* region = take(22552576);           // overlay region
  float* X0f  = region;                     // 2,097,152 (time-major layer-0 fwd)
  float* X0r  = region + 2097152;           // 2,097,152 (time-major layer-0 bwd)
  float* Qtb  = region + 4194304;           // 4 x 2,097,152
  float* Qtmp = region + 12582912;          // 2,097,152
  float* Htmp = region + 14680064;          // b-major H0 temp (early only)
  // finals overlay (sequential-phase buffers dead by then)
  float* T  = region;                       // 4,194,304
  float* Sb = region + 4194304;             // 1,048,576
  float* HH = region + 5242880;             // 4,194,304
  float* h1 = region + 9437184;             // 2,097,152
  float* h2 = region + 11534336;            // 2,097,152
  float* Ocat[2][2];                        // time-major H1 storage, stride 512
  for (int c = 0; c < 2; ++c) for (int l = 0; l < 2; ++l) Ocat[c][l] = take(4194304);
  float* S0b   = take(32768);               // 4 x 8192
  unsigned short* WtB  = (unsigned short*)take(786432);  // fp16 [cd][32][1536][8]
  unsigned short* WgkB = (unsigned short*)take(786432);  // fp16 [cd][32][1536][8]
  float* meanx = take(512);
  float* meany = take(512);
  float* invx  = take(8192);
  float* invy  = take(8192);
  float* dl    = take(8);
  float* Gbuf  = take(262144);

  // H0 = relu(F @ fc1w^T + fc1b)  (b-major temp), then spread to time-major
  gemm_k<false,true,true,false><<<dim3(4,64,1),256,0,stream>>>(
      F, fc1w, fc1b, Htmp, SD, SE, SE, SE, SD, 0,0,0);
  spread_k<<<SBN,256,0,stream>>>(Htmp, X0f, X0r);

  for (int l = 0; l < 2; ++l) {
    PTArgs pt, pg; StepArgs sta;
    sta.ldX = l ? SD2 : SD;
    sta.Wt = WtB; sta.Wgk = WgkB;
    const int ldX = sta.ldX;
    for (int cd = 0; cd < 4; ++cd) {
      const int ch = cd >> 1;  // 0 = s-channel, 1 = l-channel
      const float* X = (l == 0) ? ((cd & 1) ? X0r : X0f)
                                : (Ocat[ch][0] + (cd & 1) * SD);
      const float* wq   = gat_wq[ch] + l * SD * SD;
      const float* bq   = gat_bq[ch] + l * SD;
      const float* wk   = gat_wk[ch] + l * SD * SD;
      const float* bk   = gat_bk[ch] + l * SD;
      const float* cwih = g_wih[ch*2+0] + l * SD3 * SD;
      const float* cwhh = g_whh[ch*2+0] + l * SD3 * SD;
      const float* cbih = g_bih[ch*2+0] + l * SD3;
      const float* cbhh = g_bhh[ch*2+0] + l * SD3;
      const float* pwih = g_wih[ch*2+1] + l * SD3 * SD;
      const float* pwhh = g_whh[ch*2+1] + l * SD3 * SD;
      const float* pbih = g_bih[ch*2+1] + l * SD3;
      const float* pbhh = g_bhh[ch*2+1] + l * SD3;
      pt.wc[cd] = cwhh; pt.wp[cd] = pwih;   // step-gate weights
      pg.wc[cd] = cwih; pg.wp[cd] = pwhh;   // GK weights
      // Qtmp = X@wq^T + bq ; Qt = Qtmp@wk ; S0 = Qtmp . bk
      gemm_k<false,true,false,false><<<dim3(4,64,1),256,0,stream>>>(
          X, wq, bq, Qtmp, SD, SD, ldX, SD, SD, 0,0,0);
      gemm_k<true,false,false,false><<<dim3(4,64,1),256,0,stream>>>(
          Qtmp, wk, nullptr, Qtb + (size_t)cd*2097152, SD, SD, SD, SD, SD, 0,0,0);
      s0_k<<<SBN/4,256,0,stream>>>(Qtmp, bk, S0b + cd*SBN);
      float* H1mut = Ocat[ch][l] + (cd & 1) * SD;
      sta.Qt[cd] = Qtb + (size_t)cd*2097152;
      sta.S0[cd] = S0b + cd*SBN;
      sta.H1[cd] = H1mut;
      sta.adj[cd] = ch ? adj2 : adj1; sta.rev[cd] = cd & 1;
      sta.bc[cd]  = cbhh; sta.bp[cd]  = pbih;
      sta.bgc[cd] = cbih; sta.bgp[cd] = pbhh;
      sta.X[cd] = X;
    }
    pt.Wt = WtB;  packT_k<<<dim3(32,4),256,0,stream>>>(pt);
    pg.Wt = WgkB; packT_k<<<dim3(32,4),256,0,stream>>>(pg);

    for (int s0 = 0; s0 < SN; s0 += CS) {
      sta.s0 = s0;
      step_chunk_k<<<256,256,0,stream>>>(sta);
    }
  }

  // diff loss (row-permutation invariant -> time-major OK)
  zero_k<<<1,256,0,stream>>>(dl, 2);
  for (int l = 0; l < 2; ++l) {
    zero_k<<<4,256,0,stream>>>(meanx, 1024);  // meanx+meany contiguous
    colmean_k<<<dim3(8,32,1),256,0,stream>>>(Ocat[0][l], meanx);
    colmean_k<<<dim3(8,32,1),256,0,stream>>>(Ocat[1][l], meany);
    rownorm_k<<<SBN/4,256,0,stream>>>(Ocat[0][l], meanx, invx);
    rownorm_k<<<SBN/4,256,0,stream>>>(Ocat[1][l], meany, invy);
    zero_k<<<256,256,0,stream>>>(Gbuf, (long)SD2*SD2);
    gpart_k<<<dim3(8,8,16),256,0,stream>>>(Ocat[0][l], Ocat[1][l], meanx, meany, invx, invy, Gbuf);
    sqsum_k<<<256,256,0,stream>>>(Gbuf, dl + l);
  }

  // cross attention + final MLP (h1 accumulated from F / HSn / HLn slices)
  gemm_k<true,false,false,false><<<dim3(8,64,1),256,0,stream>>>(
      Ocat[0][1], aff1, nullptr, T, SD2, SD2, SD2, SD2, SD2, 0,0,0);
  gemm_k<false,false,false,false><<<dim3(2,1,64),256,0,stream>>>(
      T, Ocat[1][1], nullptr, Sb, SN, SD2, 64*SD2, 64*SD2, SN, SD2, SD2, (long)SN*SN);
  smax_k<<<SBN/4,256,0,stream>>>(Sb);
  gemm_k<true,false,false,false><<<dim3(8,1,64),256,0,stream>>>(
      Sb, Ocat[1][1], nullptr, HH, SD2, SN, SN, 64*SD2, SD2, (long)SN*SN, SD2, (long)SN*SD2);
  gemm_k<false,true,false,false><<<dim3(4,64,1),256,0,stream>>>(
      F, mw1, mb1, h1, SD, SE, SE, SIN, SD, 0,0,0);
  gemm_k<false,false,false,true><<<dim3(4,64,1),256,0,stream>>>(
      HH, mw1 + 1024, nullptr, h1, SD, SD2, SD2, SIN, SD, 0,0,0);
  gemm_k<true,false,false,false><<<dim3(8,64,1),256,0,stream>>>(
      Ocat[1][1], aff2, nullptr, T, SD2, SD2, SD2, SD2, SD2, 0,0,0);
  gemm_k<false,false,false,false><<<dim3(2,1,64),256,0,stream>>>(
      T, Ocat[0][1], nullptr, Sb, SN, SD2, 64*SD2, 64*SD2, SN, SD2, SD2, (long)SN*SN);
  smax_k<<<SBN/4,256,0,stream>>>(Sb);
  gemm_k<true,false,false,false><<<dim3(8,1,64),256,0,stream>>>(
      Sb, Ocat[0][1], nullptr, HH, SD2, SN, SN, 64*SD2, SD2, (long)SN*SN, SD2, (long)SN*SD2);
  gemm_k<false,false,true,true><<<dim3(4,64,1),256,0,stream>>>(
      HH, mw1 + 1536, nullptr, h1, SD, SD2, SD2, SIN, SD, 0,0,0);
  gemm_k<false,true,true,false><<<dim3(4,64,1),256,0,stream>>>(
      h1, mw2, mb2, h2, SD, SD, SD, SD, SD, 0,0,0);
  head_k<<<SBN/4,256,0,stream>>>(h2, ow, ob, out);
  fin_k<<<1,1,0,stream>>>(dl, out + SBN * SNC);
}

// Round 10
// 6758.224 us; speedup vs baseline: 6.6451x; 1.0618x over previous
//
#include <hip/hip_runtime.h>
#include <hip/hip_fp16.h>
#include <math.h>

// Problem constants
#define SB   64     // batch
#define SN   128    // seq len
#define SE   1024   // feature dim
#define SD   256    // hidden D
#define SD2  512    // 2D
#define SD3  768    // 3D
#define SIN  2048   // 4D+E
#define SNC  7
#define SBN  8192   // SB*SN
#define CS   8      // chunk steps (GK tile held in LDS)

__device__ __forceinline__ float wsum(float v){
#pragma unroll
  for (int o = 32; o; o >>= 1) v += __shfl_xor(v, o);
  return v;
}
__device__ __forceinline__ float sigm(float x){ return 1.f/(1.f + expf(-x)); }

__device__ __forceinline__ unsigned short f2h(float f){
  return __half_as_ushort(__float2half_rn(f));
}
// dot of 8 fp16 weights (packed in uint4) with 8 fp32 M values
__device__ __forceinline__ float dot8h(uint4 w, float4 ma, float4 mb, float acc){
  const float2 p0 = __half22float2(*(__half2*)&w.x);
  const float2 p1 = __half22float2(*(__half2*)&w.y);
  const float2 p2 = __half22float2(*(__half2*)&w.z);
  const float2 p3 = __half22float2(*(__half2*)&w.w);
  acc = fmaf(p0.x, ma.x, acc);
  acc = fmaf(p0.y, ma.y, acc);
  acc = fmaf(p1.x, ma.z, acc);
  acc = fmaf(p1.y, ma.w, acc);
  acc = fmaf(p2.x, mb.x, acc);
  acc = fmaf(p2.y, mb.y, acc);
  acc = fmaf(p3.x, mb.z, acc);
  acc = fmaf(p3.y, mb.w, acc);
  return acc;
}
// dot of 4 fp16 values (uint2) with 4 fp32 values
__device__ __forceinline__ float dot4h(uint2 w, float4 m, float acc){
  const float2 p0 = __half22float2(*(__half2*)&w.x);
  const float2 p1 = __half22float2(*(__half2*)&w.y);
  acc = fmaf(p0.x, m.x, acc);
  acc = fmaf(p0.y, m.y, acc);
  acc = fmaf(p1.x, m.z, acc);
  acc = fmaf(p1.y, m.w, acc);
  return acc;
}

// ---------------------------------------------------------------------------
// Generic fp32 GEMM: C[M,N] = A @ op(B) (+bias)(+acc)(+relu), batched via z.
// ---------------------------------------------------------------------------
template<bool BKMAJ, bool BIAS, bool RELU, bool ACC>
__global__ __launch_bounds__(256)
void gemm_k(const float* __restrict__ A, const float* __restrict__ Bm,
            const float* __restrict__ bias, float* __restrict__ C,
            int Nn, int K, int lda, int ldb, int ldc,
            long sA, long sB, long sC)
{
  __shared__ float As[16][132];
  __shared__ float Bs[16][68];
  const int t  = threadIdx.x;
  const int tx = t & 15, ty = t >> 4;
  const float* Ab = A + (long)blockIdx.z * sA;
  const float* Bb = Bm + (long)blockIdx.z * sB;
  float* Cb = C + (long)blockIdx.z * sC;
  const int m0 = blockIdx.y * 128, n0 = blockIdx.x * 64;
  float acc[8][4];
#pragma unroll
  for (int i = 0; i < 8; ++i)
#pragma unroll
    for (int j = 0; j < 4; ++j) acc[i][j] = 0.f;

  const int am = t >> 1, ak = (t & 1) * 8;
  int bn_ = 0, bk_ = 0;
  if (BKMAJ) { bk_ = t >> 4; bn_ = (t & 15) * 4; }
  else       { bn_ = t >> 2; bk_ = (t & 3) * 4; }

  for (int k0 = 0; k0 < K; k0 += 16) {
    const float4 a0 = *(const float4*)(Ab + (long)(m0 + am) * lda + k0 + ak);
    const float4 a1 = *(const float4*)(Ab + (long)(m0 + am) * lda + k0 + ak + 4);
    float4 b0;
    if (BKMAJ) b0 = *(const float4*)(Bb + (long)(k0 + bk_) * ldb + n0 + bn_);
    else       b0 = *(const float4*)(Bb + (long)(n0 + bn_) * ldb + k0 + bk_);
    __syncthreads();
    As[ak+0][am] = a0.x; As[ak+1][am] = a0.y; As[ak+2][am] = a0.z; As[ak+3][am] = a0.w;
    As[ak+4][am] = a1.x; As[ak+5][am] = a1.y; As[ak+6][am] = a1.z; As[ak+7][am] = a1.w;
    if (BKMAJ) { *(float4*)&Bs[bk_][bn_] = b0; }
    else { Bs[bk_+0][bn_] = b0.x; Bs[bk_+1][bn_] = b0.y; Bs[bk_+2][bn_] = b0.z; Bs[bk_+3][bn_] = b0.w; }
    __syncthreads();
#pragma unroll
    for (int kk = 0; kk < 16; ++kk) {
      float av[8], bv[4];
      *(float4*)&av[0] = *(const float4*)&As[kk][ty*8];
      *(float4*)&av[4] = *(const float4*)&As[kk][ty*8+4];
      *(float4*)&bv[0] = *(const float4*)&Bs[kk][tx*4];
#pragma unroll
      for (int ii = 0; ii < 8; ++ii)
#pragma unroll
        for (int jj = 0; jj < 4; ++jj)
          acc[ii][jj] = fmaf(av[ii], bv[jj], acc[ii][jj]);
    }
  }
#pragma unroll
  for (int ii = 0; ii < 8; ++ii) {
#pragma unroll
    for (int jj = 0; jj < 4; ++jj) {
      float v = acc[ii][jj];
      if (BIAS) v += bias[n0 + tx*4 + jj];
      const long ci = (long)(m0 + ty*8 + ii) * ldc + n0 + tx*4 + jj;
      if (ACC) v += Cb[ci];
      if (RELU) v = fmaxf(v, 0.f);
      Cb[ci] = v;
    }
  }
}

// Htmp is b-major (row b*128+n). Write time-major X0f[(n*64+b)] and reversed.
__global__ void spread_k(const float* __restrict__ src, float* __restrict__ xf,
                         float* __restrict__ xr)
{
  const int r = blockIdx.x, t = threadIdx.x;   // src row = b*128+n
  const int b = r >> 7, n = r & 127;
  const float v = src[(long)r * SD + t];
  xf[((long)(n * 64 + b)) * SD + t] = v;
  xr[((long)((127 - n) * 64 + b)) * SD + t] = v;
}

// Pack transposed fp16 weights: Wt[cd][kb8][row][8] = fp16(W[row][kb8*8+q]),
// rows 0..767 from wc, 768..1535 from wp.  Grid (32 kb8, 4 cd).
struct PTArgs { const float* wc[4]; const float* wp[4]; unsigned short* Wt; };
__global__ void packT_k(PTArgs a)
{
  const int kb8 = blockIdx.x, cd = blockIdx.y, t = threadIdx.x;
#pragma unroll
  for (int p = 0; p < 6; ++p) {
    const int r = t + 256 * p;
    const float* src = (r < 768) ? (a.wc[cd] + (long)r * SD)
                                 : (a.wp[cd] + (long)(r - 768) * SD);
    const float4 v0 = *(const float4*)(src + kb8 * 8);
    const float4 v1 = *(const float4*)(src + kb8 * 8 + 4);
    uint4 o;
    o.x = (unsigned)f2h(v0.x) | ((unsigned)f2h(v0.y) << 16);
    o.y = (unsigned)f2h(v0.z) | ((unsigned)f2h(v0.w) << 16);
    o.z = (unsigned)f2h(v1.x) | ((unsigned)f2h(v1.y) << 16);
    o.w = (unsigned)f2h(v1.z) | ((unsigned)f2h(v1.w) << 16);
    *(uint4*)(a.Wt + (((size_t)cd * 32 + kb8) * 1536 + r) * 8) = o;
  }
}

// S0[m] = Q[m,:] . bk
__global__ void s0_k(const float* __restrict__ Q, const float* __restrict__ bk,
                     float* __restrict__ S0)
{
  const int r = blockIdx.x * 4 + (threadIdx.x >> 6), lane = threadIdx.x & 63;
  const float4 q  = *(const float4*)(Q + (long)r * SD + lane * 4);
  const float4 kb = *(const float4*)(bk + lane * 4);
  float p = q.x*kb.x + q.y*kb.y + q.z*kb.z + q.w*kb.w;
  p = wsum(p);
  if (lane == 0) S0[r] = p;
}

// ---------------------------------------------------------------------------
// Chunk step kernel: CS sequential DAG steps in one launch.
// 256 blocks = one BLOCK per (cd, b) chain; blk%8 -> XCD, cd = blk&3 means
// each XCD hosts exactly one cd -> per-XCD L2 working set = Wt+Wgk (1.5 MB
// fp16) + 32 private fp16 H-shadows (2 MB) < 4 MB L2. Attention reads the
// contiguous per-chain fp16 shadow Hs[128][256]; fp32 H1 (time-major Ocat)
// is still written for downstream phases.
// ---------------------------------------------------------------------------
struct StepArgs {
  const float* Qt[4]; const float* S0[4];
  const int* adj[4]; int rev[4];
  const float* bc[4];  const float* bp[4];   // cbhh, pbih (step-gate biases)
  const float* bgc[4]; const float* bgp[4];  // cbih, pbhh (GK biases)
  const float* X[4];
  float* H1[4];                              // time-major stride SD2, col-offset baked
  unsigned short* Hh;                        // fp16 shadow [cd*64+b][128][256]
  const unsigned short* Wt;   // fp16 [cd][32][1536][8]: rows 0..767 cwhh, 768..1535 pwih
  const unsigned short* Wgk;  // fp16 [cd][32][1536][8]: rows 0..767 cwih, 768..1535 pwhh
  int ldX, s0;
};
__global__ __launch_bounds__(256, 1) void step_chunk_k(StepArgs a)
{
  __shared__ float smem[14976];   // 59.9 KB
  float* GKs  = smem;             // [CS][1536]
  float* Xs   = smem + 12288;     // [CS][256]
  float* Mlds = smem + 14336;     // [256]
  float* lg   = smem + 14592;     // [128]
  float* wgt  = smem + 14720;     // [128]
  float* adjm = smem + 14848;     // [128]

  const int blk = blockIdx.x;
  const int cd = blk & 3, b = blk >> 2;
  const int t = threadIdx.x, q = t >> 6, l = t & 63;
  const int j = t;                        // output column 0..255
  const int ldX = a.ldX, s0 = a.s0;
  const float* Xp  = a.X[cd];
  float* H1 = a.H1[cd];
  unsigned short* Hs = a.Hh + ((size_t)(cd * 64 + b)) * 128 * 256;
  const float* Qtp = a.Qt[cd];
  const float* S0p = a.S0[cd];
  const int*   adjp = a.adj[cd];
  const int    rev  = a.rev[cd];

  // hoisted biases for this thread's column j
  const float bc0 = a.bc[cd][j],  bc1 = a.bc[cd][256+j],  bc2 = a.bc[cd][512+j];
  const float bp0 = a.bp[cd][j],  bp1 = a.bp[cd][256+j],  bp2 = a.bp[cd][512+j];

  // ---- GK phase: GKs[s][g*256+j] = X[s0+s,b] . Wgk_row(g*256+j) + bias ----
#pragma unroll
  for (int s = 0; s < CS; ++s)
    Xs[s*256 + t] = Xp[((long)(s0+s)*64 + b)*ldX + t];
  __syncthreads();
  {
    float gacc[6][CS];
#pragma unroll
    for (int g = 0; g < 6; ++g)
#pragma unroll
      for (int s = 0; s < CS; ++s) gacc[g][s] = 0.f;
    const unsigned short* wbase = a.Wgk + ((size_t)cd*32*1536 + j)*8;
    for (int kb8 = 0; kb8 < 32; ++kb8) {
      const uint4* wr = (const uint4*)(wbase + (size_t)kb8*12288);
      uint4 w[6];
#pragma unroll
      for (int g = 0; g < 6; ++g) w[g] = wr[g*256];   // 1 row = 1 uint4; gate stride 256 rows
#pragma unroll
      for (int s = 0; s < CS; ++s) {
        const float4 xa = *(const float4*)&Xs[s*256 + kb8*8];
        const float4 xb = *(const float4*)&Xs[s*256 + kb8*8 + 4];
#pragma unroll
        for (int g = 0; g < 6; ++g)
          gacc[g][s] = dot8h(w[g], xa, xb, gacc[g][s]);
      }
    }
#pragma unroll
    for (int g = 0; g < 6; ++g) {
      const float bg = (g < 3) ? a.bgc[cd][g*256 + j] : a.bgp[cd][(g-3)*256 + j];
#pragma unroll
      for (int s = 0; s < CS; ++s)
        GKs[s*1536 + g*256 + j] = gacc[g][s] + bg;
    }
  }
  __syncthreads();

  // ---- CS sequential steps ----
  for (int i = s0; i < s0 + CS; ++i) {
    if (i == 0) {
      Mlds[t] = 0.f;
      __syncthreads();
    } else {
      if (t < 128) {
        const int ii = rev ? (SN-1-i) : i;
        const int nn = rev ? (SN-1-t) : t;
        adjm[t] = (float)adjp[((long)b*SN + ii)*SN + nn];
      }
      const float4 q4 = *(const float4*)(Qtp + ((long)i*64 + b)*SD + l*4);
      for (int n = q; n < i; n += 4) {
        const uint2 hv = *(const uint2*)(Hs + (size_t)n*256 + l*4);
        float p = dot4h(hv, q4, 0.f);
        p = wsum(p);
        if (l == 0) lg[n] = p;
      }
      __syncthreads();
      if (q == 0) {
        const float s0v = S0p[i*64 + b];
        const float v0 = (l < i)    ? (lg[l]    + s0v - (1.f - adjm[l]   )*1e30f) : -3.0e38f;
        const float v1 = (l+64 < i) ? (lg[l+64] + s0v - (1.f - adjm[l+64])*1e30f) : -3.0e38f;
        float mx = fmaxf(v0, v1);
#pragma unroll
        for (int o = 32; o; o >>= 1) mx = fmaxf(mx, __shfl_xor(mx, o));
        const float e0 = (l < i)    ? expf(v0 - mx) : 0.f;
        const float e1 = (l+64 < i) ? expf(v1 - mx) : 0.f;
        float sum = e0 + e1;
#pragma unroll
        for (int o = 32; o; o >>= 1) sum += __shfl_xor(sum, o);
        const float inv = 1.f / sum;
        if (l < i)    wgt[l]    = e0 * inv;
        if (l+64 < i) wgt[l+64] = e1 * inv;
      }
      __syncthreads();
      float acc = 0.f;
      const __half* Hsh = (const __half*)Hs;
#pragma unroll 4
      for (int n = 0; n < i; ++n)
        acc = fmaf(wgt[n], __half2float(Hsh[(size_t)n*256 + t]), acc);
      Mlds[t] = acc;
      __syncthreads();
    }

    // gates: 6 rows (g*256+j) x M, fp16 weights (row = 1 uint4 -> offsets g*256)
    float a0 = 0.f, a1 = 0.f, a2 = 0.f, a3 = 0.f, a4 = 0.f, a5 = 0.f;
    {
      const unsigned short* wb = a.Wt + ((size_t)cd*32*1536 + j)*8;
#pragma unroll 2
      for (int kb8 = 0; kb8 < 32; ++kb8) {
        const float4 ma = *(const float4*)&Mlds[kb8*8];
        const float4 mb = *(const float4*)&Mlds[kb8*8 + 4];
        const uint4* wr = (const uint4*)(wb + (size_t)kb8*12288);
        const uint4 w0 = wr[0];
        const uint4 w1 = wr[256];
        const uint4 w2 = wr[512];
        const uint4 w3 = wr[768];
        const uint4 w4 = wr[1024];
        const uint4 w5 = wr[1280];
        a0 = dot8h(w0, ma, mb, a0);
        a1 = dot8h(w1, ma, mb, a1);
        a2 = dot8h(w2, ma, mb, a2);
        a3 = dot8h(w3, ma, mb, a3);
        a4 = dot8h(w4, ma, mb, a4);
        a5 = dot8h(w5, ma, mb, a5);
      }
    }
    // GRU elementwise + H1 row write (fp32 time-major + fp16 shadow)
    {
      const int s = i - s0;
      const float gic_r = GKs[s*1536 + j];
      const float gic_z = GKs[s*1536 + 256 + j];
      const float gic_n = GKs[s*1536 + 512 + j];
      const float ghp_r = GKs[s*1536 + 768 + j];
      const float ghp_z = GKs[s*1536 + 1024 + j];
      const float ghp_n = GKs[s*1536 + 1280 + j];
      const float xj = Xp[((long)i*64 + b)*ldX + j];
      const float mj = Mlds[j];
      const float rC = sigm(gic_r + a0 + bc0);
      const float zC = sigm(gic_z + a1 + bc1);
      const float nC = tanhf(gic_n + rC * (a2 + bc2));
      const float Cc = (1.f - zC) * nC + zC * mj;
      const float rP = sigm(a3 + bp0 + ghp_r);
      const float zP = sigm(a4 + bp1 + ghp_z);
      const float nP = tanhf(a5 + bp2 + rP * ghp_n);
      const float hval = Cc + (1.f - zP) * nP + zP * xj;
      H1[((long)i*64 + b)*SD2 + j] = hval;
      Hs[(size_t)i*256 + j] = f2h(hval);
    }
    __threadfence_block();
    __syncthreads();
  }
}

__global__ void zero_k(float* p, long n)
{
  for (long idx = (long)blockIdx.x * 256 + threadIdx.x; idx < n; idx += (long)gridDim.x * 256)
    p[idx] = 0.f;
}

// column means of (8192 x 512), grid (8 colblocks, 32 rowslices), atomicAdd
__global__ void colmean_k(const float* __restrict__ X, float* __restrict__ mean)
{
  __shared__ float red[256];
  const int c = blockIdx.x * 64 + (threadIdx.x & 63), rq = threadIdx.x >> 6;
  const int r0 = blockIdx.y * 256;
  float acc = 0.f;
  for (int r = r0 + rq; r < r0 + 256; r += 4) acc += X[(long)r * SD2 + c];
  red[threadIdx.x] = acc;
  __syncthreads();
  if (threadIdx.x < 64) {
    const float s = red[threadIdx.x] + red[64 + threadIdx.x] + red[128 + threadIdx.x] + red[192 + threadIdx.x];
    atomicAdd(&mean[c], s * (1.f / 8192.f));
  }
}

__global__ void rownorm_k(const float* __restrict__ X, const float* __restrict__ mean,
                          float* __restrict__ inv)
{
  const int r = blockIdx.x * 4 + (threadIdx.x >> 6), lane = threadIdx.x & 63;
  const float* xp = X + (long)r * SD2 + lane * 8;
  const float4 v0 = *(const float4*)xp;
  const float4 v1 = *(const float4*)(xp + 4);
  const float4 m0 = *(const float4*)(mean + lane * 8);
  const float4 m1 = *(const float4*)(mean + lane * 8 + 4);
  float ss = 0.f, d;
  d = v0.x - m0.x; ss += d*d;  d = v0.y - m0.y; ss += d*d;
  d = v0.z - m0.z; ss += d*d;  d = v0.w - m0.w; ss += d*d;
  d = v1.x - m1.x; ss += d*d;  d = v1.y - m1.y; ss += d*d;
  d = v1.z - m1.z; ss += d*d;  d = v1.w - m1.w; ss += d*d;
  ss = wsum(ss);
  if (lane == 0) inv[r] = 1.f / (sqrtf(ss) + 1e-6f);
}

// partial G += xhat^T yhat over K slice; grid (8, 8, 16)
__global__ __launch_bounds__(256)
void gpart_k(const float* __restrict__ X, const float* __restrict__ Y,
             const float* __restrict__ mx, const float* __restrict__ my,
             const float* __restrict__ ix, const float* __restrict__ iy,
             float* __restrict__ G)
{
  __shared__ float As[16][68];
  __shared__ float Bs[16][68];
  __shared__ float mxs[64], mys[64];
  const int t = threadIdx.x, tx = t & 15, ty = t >> 4;
  const int ci = blockIdx.y * 64, cj = blockIdx.x * 64;
  if (t < 64) { mxs[t] = mx[ci + t]; mys[t] = my[cj + t]; }
  float acc[4][4];
#pragma unroll
  for (int ii = 0; ii < 4; ++ii)
#pragma unroll
    for (int jj = 0; jj < 4; ++jj) acc[ii][jj] = 0.f;
  const int rl = t >> 4, c4 = (t & 15) * 4;
  __syncthreads();
  const int kend = blockIdx.z * 512 + 512;
  for (int kb = blockIdx.z * 512; kb < kend; kb += 16) {
    const int r = kb + rl;
    const float4 xv = *(const float4*)(X + (long)r * SD2 + ci + c4);
    const float4 yv = *(const float4*)(Y + (long)r * SD2 + cj + c4);
    const float vx = ix[r], vy = iy[r];
    __syncthreads();
    As[rl][c4+0] = (xv.x - mxs[c4+0]) * vx; As[rl][c4+1] = (xv.y - mxs[c4+1]) * vx;
    As[rl][c4+2] = (xv.z - mxs[c4+2]) * vx; As[rl][c4+3] = (xv.w - mxs[c4+3]) * vx;
    Bs[rl][c4+0] = (yv.x - mys[c4+0]) * vy; Bs[rl][c4+1] = (yv.y - mys[c4+1]) * vy;
    Bs[rl][c4+2] = (yv.z - mys[c4+2]) * vy; Bs[rl][c4+3] = (yv.w - mys[c4+3]) * vy;
    __syncthreads();
#pragma unroll
    for (int kk = 0; kk < 16; ++kk) {
      float av[4], bv[4];
      *(float4*)&av[0] = *(const float4*)&As[kk][ty*4];
      *(float4*)&bv[0] = *(const float4*)&Bs[kk][tx*4];
#pragma unroll
      for (int ii = 0; ii < 4; ++ii)
#pragma unroll
        for (int jj = 0; jj < 4; ++jj)
          acc[ii][jj] = fmaf(av[ii], bv[jj], acc[ii][jj]);
    }
  }
#pragma unroll
  for (int ii = 0; ii < 4; ++ii)
#pragma unroll
    for (int jj = 0; jj < 4; ++jj)
      atomicAdd(&G[(long)(ci + ty*4 + ii) * SD2 + cj + tx*4 + jj], acc[ii][jj]);
}

__global__ void sqsum_k(const float* __restrict__ G, float* __restrict__ dl)
{
  __shared__ float red[4];
  float s = 0.f;
  const long base = (long)blockIdx.x * 1024;
#pragma unroll
  for (int it = 0; it < 4; ++it) { const float v = G[base + it*256 + threadIdx.x]; s += v*v; }
  s = wsum(s);
  const int lane = threadIdx.x & 63, wv = threadIdx.x >> 6;
  if (lane == 0) red[wv] = s;
  __syncthreads();
  if (threadIdx.x == 0) atomicAdd(dl, red[0] + red[1] + red[2] + red[3]);
}

// softmax over rows of length 128 (in-place)
__global__ void smax_k(float* __restrict__ S)
{
  const int r = blockIdx.x * 4 + (threadIdx.x >> 6), lane = threadIdx.x & 63;
  float* p = S + (long)r * SN;
  const float v0 = p[lane], v1 = p[lane + 64];
  float mx = fmaxf(v0, v1);
#pragma unroll
  for (int o = 32; o; o >>= 1) mx = fmaxf(mx, __shfl_xor(mx, o));
  const float e0 = expf(v0 - mx), e1 = expf(v1 - mx);
  float s = e0 + e1;
#pragma unroll
  for (int o = 32; o; o >>= 1) s += __shfl_xor(s, o);
  const float inv = 1.f / s;
  p[lane] = e0 * inv; p[lane + 64] = e1 * inv;
}

__global__ void head_k(const float* __restrict__ H, const float* __restrict__ W,
                       const float* __restrict__ bo, float* __restrict__ out)
{
  const int r = blockIdx.x * 4 + (threadIdx.x >> 6), lane = threadIdx.x & 63;
  const float4 h = *(const float4*)(H + (long)r * SD + lane * 4);
#pragma unroll
  for (int c = 0; c < SNC; ++c) {
    const float4 w = *(const float4*)(W + (long)c * SD + lane * 4);
    float p = h.x*w.x + h.y*w.y + h.z*w.z + h.w*w.w;
    p = wsum(p);
    if (lane == 0) out[(long)r * SNC + c] = p + bo[c];
  }
}

__global__ void fin_k(const float* __restrict__ dl, float* __restrict__ out)
{
  out[0] = (dl[0] + dl[1]) * (0.3f / (512.f * 512.f));
}

// ---------------------------------------------------------------------------
extern "C" void kernel_launch(void* const* d_in, const int* in_sizes, int n_in,
                              void* d_out, int out_size, void* d_ws, size_t ws_size,
                              hipStream_t stream)
{
  (void)in_sizes; (void)n_in; (void)out_size; (void)ws_size;
  const float* F    = (const float*)d_in[0];
  const int*   adj1 = (const int*)  d_in[1];
  const int*   adj2 = (const int*)  d_in[2];
  const float* fc1w = (const float*)d_in[6];
  const float* fc1b = (const float*)d_in[7];
  const float *g_wih[4], *g_whh[4], *g_bih[4], *g_bhh[4];  // gcs, gps, gcl, gpl
  for (int g = 0; g < 4; ++g) {
    g_wih[g] = (const float*)d_in[8 + g*4 + 0];
    g_whh[g] = (const float*)d_in[8 + g*4 + 1];
    g_bih[g] = (const float*)d_in[8 + g*4 + 2];
    g_bhh[g] = (const float*)d_in[8 + g*4 + 3];
  }
  const float* gat_wq[2] = {(const float*)d_in[24], (const float*)d_in[28]};
  const float* gat_bq[2] = {(const float*)d_in[25], (const float*)d_in[29]};
  const float* gat_wk[2] = {(const float*)d_in[26], (const float*)d_in[30]};
  const float* gat_bk[2] = {(const float*)d_in[27], (const float*)d_in[31]};
  const float* aff1 = (const float*)d_in[32];
  const float* aff2 = (const float*)d_in[33];
  const float* mw1  = (const float*)d_in[34];
  const float* mb1  = (const float*)d_in[35];
  const float* mw2  = (const float*)d_in[36];
  const float* mb2  = (const float*)d_in[37];
  const float* ow   = (const float*)d_in[38];
  const float* ob   = (const float*)d_in[39];
  float* out = (float*)d_out;

  // ---- workspace layout ----
  float* ws = (float*)d_ws;
  size_t off = 0;
  auto take = [&](size_t nf){ float* p = ws + off; off += nf; return p; };
  float* region = take(22552576);           // overlay region
  float* X0f  = region;                     // 2,097,152 (time-major layer-0 fwd)
  float* X0r  = region + 2097152;           // 2,097,152 (time-major layer-0 bwd)
  float* Qtb  = region + 4194304;           // 4 x 2,097,152
  float* Qtmp = region + 12582912;          // 2,097,152
  float* Htmp = region + 14680064;          // b-major H0 temp (early only)
  // finals overlay (sequential-phase buffers dead by then)
  float* T  = region;                       // 4,194,304
  float* Sb = region + 4194304;             // 1,048,576
  float* HH = region + 5242880;             // 4,194,304
  float* h1 = region + 9437184;             // 2,097,152
  float* h2 = region + 11534336;            // 2,097,152
  float* Ocat[2][2];                        // time-major H1 storage, stride 512
  for (int c = 0; c < 2; ++c) for (int l = 0; l < 2; ++l) Ocat[c][l] = take(4194304);
  float* S0b   = take(32768);               // 4 x 8192
  unsigned short* WtB  = (unsigned short*)take(786432);  // fp16 [cd][32][1536][8]
  unsigned short* WgkB = (unsigned short*)take(786432);  // fp16 [cd][32][1536][8]
  unsigned short* HhB  = (unsigned short*)take(4194304); // fp16 shadow [256][128][256]
  float* meanx = take(512);
  float* meany = take(512);
  float* invx  = take(8192);
  float* invy  = take(8192);
  float* dl    = take(8);
  float* Gbuf  = take(262144);

  // H0 = relu(F @ fc1w^T + fc1b)  (b-major temp), then spread to time-major
  gemm_k<false,true,true,false><<<dim3(4,64,1),256,0,stream>>>(
      F, fc1w, fc1b, Htmp, SD, SE, SE, SE, SD, 0,0,0);
  spread_k<<<SBN,256,0,stream>>>(Htmp, X0f, X0r);

  for (int l = 0; l < 2; ++l) {
    PTArgs pt, pg; StepArgs sta;
    sta.ldX = l ? SD2 : SD;
    sta.Wt = WtB; sta.Wgk = WgkB; sta.Hh = HhB;
    const int ldX = sta.ldX;
    for (int cd = 0; cd < 4; ++cd) {
      const int ch = cd >> 1;  // 0 = s-channel, 1 = l-channel
      const float* X = (l == 0) ? ((cd & 1) ? X0r : X0f)
                                : (Ocat[ch][0] + (cd & 1) * SD);
      const float* wq   = gat_wq[ch] + l * SD * SD;
      const float* bq   = gat_bq[ch] + l * SD;
      const float* wk   = gat_wk[ch] + l * SD * SD;
      const float* bk   = gat_bk[ch] + l * SD;
      const float* cwih = g_wih[ch*2+0] + l * SD3 * SD;
      const float* cwhh = g_whh[ch*2+0] + l * SD3 * SD;
      const float* cbih = g_bih[ch*2+0] + l * SD3;
      const float* cbhh = g_bhh[ch*2+0] + l * SD3;
      const float* pwih = g_wih[ch*2+1] + l * SD3 * SD;
      const float* pwhh = g_whh[ch*2+1] + l * SD3 * SD;
      const float* pbih = g_bih[ch*2+1] + l * SD3;
      const float* pbhh = g_bhh[ch*2+1] + l * SD3;
      pt.wc[cd] = cwhh; pt.wp[cd] = pwih;   // step-gate weights
      pg.wc[cd] = cwih; pg.wp[cd] = pwhh;   // GK weights
      // Qtmp = X@wq^T + bq ; Qt = Qtmp@wk ; S0 = Qtmp . bk
      gemm_k<false,true,false,false><<<dim3(4,64,1),256,0,stream>>>(
          X, wq, bq, Qtmp, SD, SD, ldX, SD, SD, 0,0,0);
      gemm_k<true,false,false,false><<<dim3(4,64,1),256,0,stream>>>(
          Qtmp, wk, nullptr, Qtb + (size_t)cd*2097152, SD, SD, SD, SD, SD, 0,0,0);
      s0_k<<<SBN/4,256,0,stream>>>(Qtmp, bk, S0b + cd*SBN);
      float* H1mut = Ocat[ch][l] + (cd & 1) * SD;
      sta.Qt[cd] = Qtb + (size_t)cd*2097152;
      sta.S0[cd] = S0b + cd*SBN;
      sta.H1[cd] = H1mut;
      sta.adj[cd] = ch ? adj2 : adj1; sta.rev[cd] = cd & 1;
      sta.bc[cd]  = cbhh; sta.bp[cd]  = pbih;
      sta.bgc[cd] = cbih; sta.bgp[cd] = pbhh;
      sta.X[cd] = X;
    }
    pt.Wt = WtB;  packT_k<<<dim3(32,4),256,0,stream>>>(pt);
    pg.Wt = WgkB; packT_k<<<dim3(32,4),256,0,stream>>>(pg);

    for (int s0 = 0; s0 < SN; s0 += CS) {
      sta.s0 = s0;
      step_chunk_k<<<256,256,0,stream>>>(sta);
    }
  }

  // diff loss (row-permutation invariant -> time-major OK)
  zero_k<<<1,256,0,stream>>>(dl, 2);
  for (int l = 0; l < 2; ++l) {
    zero_k<<<4,256,0,stream>>>(meanx, 1024);  // meanx+meany contiguous
    colmean_k<<<dim3(8,32,1),256,0,stream>>>(Ocat[0][l], meanx);
    colmean_k<<<dim3(8,32,1),256,0,stream>>>(Ocat[1][l], meany);
    rownorm_k<<<SBN/4,256,0,stream>>>(Ocat[0][l], meanx, invx);
    rownorm_k<<<SBN/4,256,0,stream>>>(Ocat[1][l], meany, invy);
    zero_k<<<256,256,0,stream>>>(Gbuf, (long)SD2*SD2);
    gpart_k<<<dim3(8,8,16),256,0,stream>>>(Ocat[0][l], Ocat[1][l], meanx, meany, invx, invy, Gbuf);
    sqsum_k<<<256,256,0,stream>>>(Gbuf, dl + l);
  }

  // cross attention + final MLP (h1 accumulated from F / HSn / HLn slices)
  gemm_k<true,false,false,false><<<dim3(8,64,1),256,0,stream>>>(
      Ocat[0][1], aff1, nullptr, T, SD2, SD2, SD2, SD2, SD2, 0,0,0);
  gemm_k<false,false,false,false><<<dim3(2,1,64),256,0,stream>>>(
      T, Ocat[1][1], nullptr, Sb, SN, SD2, 64*SD2, 64*SD2, SN, SD2, SD2, (long)SN*SN);
  smax_k<<<SBN/4,256,0,stream>>>(Sb);
  gemm_k<true,false,false,false><<<dim3(8,1,64),256,0,stream>>>(
      Sb, Ocat[1][1], nullptr, HH, SD2, SN, SN, 64*SD2, SD2, (long)SN*SN, SD2, (long)SN*SD2);
  gemm_k<false,true,false,false><<<dim3(4,64,1),256,0,stream>>>(
      F, mw1, mb1, h1, SD, SE, SE, SIN, SD, 0,0,0);
  gemm_k<false,false,false,true><<<dim3(4,64,1),256,0,stream>>>(
      HH, mw1 + 1024, nullptr, h1, SD, SD2, SD2, SIN, SD, 0,0,0);
  gemm_k<true,false,false,false><<<dim3(8,64,1),256,0,stream>>>(
      Ocat[1][1], aff2, nullptr, T, SD2, SD2, SD2, SD2, SD2, 0,0,0);
  gemm_k<false,false,false,false><<<dim3(2,1,64),256,0,stream>>>(
      T, Ocat[0][1], nullptr, Sb, SN, SD2, 64*SD2, 64*SD2, SN, SD2, SD2, (long)SN*SN);
  smax_k<<<SBN/4,256,0,stream>>>(Sb);
  gemm_k<true,false,false,false><<<dim3(8,1,64),256,0,stream>>>(
      Sb, Ocat[0][1], nullptr, HH, SD2, SN, SN, 64*SD2, SD2, (long)SN*SN, SD2, (long)SN*SD2);
  gemm_k<false,false,true,true><<<dim3(4,64,1),256,0,stream>>>(
      HH, mw1 + 1536, nullptr, h1, SD, SD2, SD2, SIN, SD, 0,0,0);
  gemm_k<false,true,true,false><<<dim3(4,64,1),256,0,stream>>>(
      h1, mw2, mb2, h2, SD, SD, SD, SD, SD, 0,0,0);
  head_k<<<SBN/4,256,0,stream>>>(h2, ow, ob, out);
  fin_k<<<1,1,0,stream>>>(dl, out + SBN * SNC);
}